// Round 3
// baseline (5477.072 us; speedup 1.0000x reference)
//
#include <hip/hip_runtime.h>

#define N_USERS 100000
#define N_ITEMS 50000
#define NTOT    150000
#define DD      64
#define NNZV    6400000
#define ALPHA_  0.3f

static constexpr size_t SZ  = (size_t)NTOT * DD;

// ================= wave-per-16-rows GEMM, N=64, fused bias + L2-norm ========
// Block = 1 wave (64 threads). Lane = output column. Rows are wave-uniform ->
// A loads go through the scalar path (s_load_dwordx4), W loads are coalesced
// 256B vector loads (L2-resident, reused x16 rows).
__global__ __launch_bounds__(64) void gemm_rows16(
    const float* __restrict__ A, const float* __restrict__ W,
    const float* __restrict__ bias, float* __restrict__ C,
    int M, int K, int ldc, int do_norm)
{
    const int lane  = threadIdx.x;
    const int rbase = blockIdx.x * 16;
    if (rbase >= M) return;

    float acc[16];
    #pragma unroll
    for (int i = 0; i < 16; ++i) acc[i] = 0.f;

    const float* Ab = A + (size_t)rbase * K;

    for (int k = 0; k < K; k += 4) {
        const float w0 = W[(size_t)(k + 0) * DD + lane];
        const float w1 = W[(size_t)(k + 1) * DD + lane];
        const float w2 = W[(size_t)(k + 2) * DD + lane];
        const float w3 = W[(size_t)(k + 3) * DD + lane];
        #pragma unroll
        for (int i = 0; i < 16; ++i) {
            const float4 a = *(const float4*)(Ab + (size_t)i * K + k);  // wave-uniform
            acc[i] += a.x * w0 + a.y * w1 + a.z * w2 + a.w * w3;
        }
    }

    const float bv = bias[lane];
    #pragma unroll
    for (int i = 0; i < 16; ++i) {
        float v = acc[i] + bv;
        if (do_norm) {
            float s = v * v;
            #pragma unroll
            for (int off = 32; off > 0; off >>= 1) s += __shfl_xor(s, off);
            v = v / fmaxf(sqrtf(s), 1e-12f);
        }
        C[(size_t)(rbase + i) * ldc + lane] = v;
    }
}

// ================= interleave user prefs into X[row][0:64|64:128] ===========
__global__ __launch_bounds__(256) void build_user(const float4* __restrict__ ip,
                                                  const float4* __restrict__ tp,
                                                  float4* __restrict__ X)
{
    int i = blockIdx.x * 256 + threadIdx.x;
    if (i >= N_USERS * 16) return;
    int row = i >> 4, q = i & 15;
    X[(size_t)row * 32 + q]      = ip[i];
    X[(size_t)row * 32 + 16 + q] = tp[i];
}

// ================= counting sort by row =====================================
__global__ __launch_bounds__(256) void hist_k(const int* __restrict__ rows, int* __restrict__ hist)
{
    int i = blockIdx.x * 256 + threadIdx.x;
    if (i < NNZV) atomicAdd(&hist[rows[i]], 1);
}

__global__ __launch_bounds__(256) void scan_block(const int* __restrict__ in, int* __restrict__ out,
                                                  int* __restrict__ partials, int n)
{
    __shared__ int sh[256];
    int t = threadIdx.x;
    int base = blockIdx.x * 1024 + t * 4;
    int v0 = 0, v1 = 0, v2 = 0, v3 = 0;
    if (base + 3 < n) { int4 x = *(const int4*)(in + base); v0 = x.x; v1 = x.y; v2 = x.z; v3 = x.w; }
    else {
        if (base     < n) v0 = in[base];
        if (base + 1 < n) v1 = in[base + 1];
        if (base + 2 < n) v2 = in[base + 2];
        if (base + 3 < n) v3 = in[base + 3];
    }
    int tsum = v0 + v1 + v2 + v3;
    sh[t] = tsum;
    __syncthreads();
    for (int off = 1; off < 256; off <<= 1) {
        int x = 0;
        if (t >= off) x = sh[t - off];
        __syncthreads();
        sh[t] += x;
        __syncthreads();
    }
    int texcl = sh[t] - tsum;
    if (t == 255) partials[blockIdx.x] = sh[255];
    int e0 = texcl, e1 = e0 + v0, e2 = e1 + v1, e3 = e2 + v2;
    if (base + 3 < n) { *(int4*)(out + base) = make_int4(e0, e1, e2, e3); }
    else {
        if (base     < n) out[base]     = e0;
        if (base + 1 < n) out[base + 1] = e1;
        if (base + 2 < n) out[base + 2] = e2;
        if (base + 3 < n) out[base + 3] = e3;
    }
}

__global__ __launch_bounds__(256) void scan_partials(int* __restrict__ p, int np)
{
    __shared__ int sh[256];
    int t = threadIdx.x;
    int v = (t < np) ? p[t] : 0;
    sh[t] = v;
    __syncthreads();
    for (int off = 1; off < 256; off <<= 1) {
        int x = 0;
        if (t >= off) x = sh[t - off];
        __syncthreads();
        sh[t] += x;
        __syncthreads();
    }
    if (t < np) p[t] = sh[t] - v;
}

__global__ __launch_bounds__(256) void add_offsets(int* __restrict__ out,
                                                   const int* __restrict__ partials, int n)
{
    int i = blockIdx.x * 256 + threadIdx.x;
    if (i < n) out[i] += partials[i >> 10];
}

__global__ void set_tail(int* __restrict__ rstart)
{
    if (threadIdx.x == 0 && blockIdx.x == 0) rstart[NTOT] = NNZV;
}

__global__ __launch_bounds__(256) void copy4(const float4* __restrict__ src,
                                             float4* __restrict__ dst, int n4)
{
    int i = blockIdx.x * 256 + threadIdx.x;
    if (i < n4) dst[i] = src[i];
}

__global__ __launch_bounds__(256) void scatter_k(
    const float* __restrict__ vals, const int* __restrict__ rows, const int* __restrict__ cols,
    int* __restrict__ cursor, int2* __restrict__ spair)
{
    int i = blockIdx.x * 256 + threadIdx.x;
    if (i >= NNZV) return;
    int r = rows[i];
    int p = atomicAdd(&cursor[r], 1);
    spair[p] = make_int2(__float_as_int(vals[i]), cols[i]);
}

// ================= column-parallel per-row SpMM, no atomics, no shuffles ====
// 256 threads = 2 rows x 128 cols. (val,col) pairs are row-uniform -> scalar
// loads; X gathers are 512B coalesced per row; unroll x4 for MLP.
__global__ __launch_bounds__(256) void spmm_cols(
    const int2* __restrict__ spair, const int* __restrict__ rstart,
    const float* __restrict__ Xin, float* __restrict__ Xout)
{
    int row = (blockIdx.x << 1) + (threadIdx.x >> 7);
    int c   = threadIdx.x & 127;
    if (row >= NTOT) return;
    int beg = rstart[row];
    int end = rstart[row + 1];
    float a = 0.f;
    int j = beg;
    for (; j + 4 <= end; j += 4) {
        int2 p0 = spair[j];
        int2 p1 = spair[j + 1];
        int2 p2 = spair[j + 2];
        int2 p3 = spair[j + 3];
        float x0 = Xin[(size_t)p0.y * 128 + c];
        float x1 = Xin[(size_t)p1.y * 128 + c];
        float x2 = Xin[(size_t)p2.y * 128 + c];
        float x3 = Xin[(size_t)p3.y * 128 + c];
        a += __int_as_float(p0.x) * x0;
        a += __int_as_float(p1.x) * x1;
        a += __int_as_float(p2.x) * x2;
        a += __int_as_float(p3.x) * x3;
    }
    for (; j < end; ++j) {
        int2 p = spair[j];
        a += __int_as_float(p.x) * Xin[(size_t)p.y * 128 + c];
    }
    size_t o = (size_t)row * 128 + c;
    Xout[o] = a + ALPHA_ * Xin[o];
}

// ================= fallback (round-1) kernels ===============================
__global__ __launch_bounds__(256) void gemm_bias(
    const float* __restrict__ A, const float* __restrict__ W,
    const float* __restrict__ bias, float* __restrict__ C, int M, int K, int ldc)
{
    __shared__ float As[16][64];
    __shared__ float Bs[16][64];
    const int t  = threadIdx.x;
    const int tx = t & 15, ty = t >> 4;
    const int lr = t >> 2;
    const int lk = (t & 3) << 2;
    const int brow = t >> 4;
    const int bc   = (t & 15) << 2;
    const int block_row = blockIdx.x << 6;

    float acc[4][4] = {{0.f,0.f,0.f,0.f},{0.f,0.f,0.f,0.f},{0.f,0.f,0.f,0.f},{0.f,0.f,0.f,0.f}};
    const int grow = block_row + lr;
    const bool arow_ok = (grow < M);
    const float* Aptr = A + (size_t)grow * K;

    for (int k0 = 0; k0 < K; k0 += 16) {
        float4 av = make_float4(0.f, 0.f, 0.f, 0.f);
        if (arow_ok) av = *(const float4*)(Aptr + k0 + lk);
        As[lk+0][lr] = av.x; As[lk+1][lr] = av.y; As[lk+2][lr] = av.z; As[lk+3][lr] = av.w;
        *(float4*)&Bs[brow][bc] = *(const float4*)(W + (size_t)(k0 + brow) * DD + bc);
        __syncthreads();
        #pragma unroll
        for (int k = 0; k < 16; ++k) {
            float4 a = *(const float4*)&As[k][ty << 2];
            float4 b = *(const float4*)&Bs[k][tx << 2];
            acc[0][0] += a.x*b.x; acc[0][1] += a.x*b.y; acc[0][2] += a.x*b.z; acc[0][3] += a.x*b.w;
            acc[1][0] += a.y*b.x; acc[1][1] += a.y*b.y; acc[1][2] += a.y*b.z; acc[1][3] += a.y*b.w;
            acc[2][0] += a.z*b.x; acc[2][1] += a.z*b.y; acc[2][2] += a.z*b.z; acc[2][3] += a.z*b.w;
            acc[3][0] += a.w*b.x; acc[3][1] += a.w*b.y; acc[3][2] += a.w*b.z; acc[3][3] += a.w*b.w;
        }
        __syncthreads();
    }
    const float4 bv = *(const float4*)(bias + (tx << 2));
    #pragma unroll
    for (int i = 0; i < 4; ++i) {
        int row = block_row + (ty << 2) + i;
        if (row < M) {
            float4 o = make_float4(acc[i][0] + bv.x, acc[i][1] + bv.y,
                                   acc[i][2] + bv.z, acc[i][3] + bv.w);
            *(float4*)(C + (size_t)row * ldc + (tx << 2)) = o;
        }
    }
}

__global__ __launch_bounds__(256) void l2norm_rows(float* __restrict__ x, int nrows, int ld)
{
    int row  = blockIdx.x * 4 + (threadIdx.x >> 6);
    int lane = threadIdx.x & 63;
    if (row >= nrows) return;
    float v = x[(size_t)row * ld + lane];
    float s = v * v;
    #pragma unroll
    for (int off = 32; off > 0; off >>= 1) s += __shfl_xor(s, off);
    float n = sqrtf(s);
    x[(size_t)row * ld + lane] = v / fmaxf(n, 1e-12f);
}

__global__ __launch_bounds__(256) void scale4(const float4* __restrict__ src,
                                              float4* __restrict__ dst, int n4)
{
    int i = blockIdx.x * 256 + threadIdx.x;
    if (i < n4) {
        float4 v = src[i];
        dst[i] = make_float4(ALPHA_*v.x, ALPHA_*v.y, ALPHA_*v.z, ALPHA_*v.w);
    }
}

__global__ __launch_bounds__(256) void spmm_atomic(
    const float* __restrict__ vals, const int* __restrict__ rows,
    const int* __restrict__ cols, const float* __restrict__ x,
    float* __restrict__ out, int nnz)
{
    long long tid = (long long)blockIdx.x * 256 + threadIdx.x;
    int g = (int)(tid >> 4);
    if (g >= nnz) return;
    int lane = (int)(tid & 15);
    float v = vals[g];
    int r = rows[g], c = cols[g];
    float4 xv = *((const float4*)(x + (size_t)c * DD) + lane);
    float* o = out + (size_t)r * DD + (lane << 2);
    atomicAdd(o + 0, v * xv.x);
    atomicAdd(o + 1, v * xv.y);
    atomicAdd(o + 2, v * xv.z);
    atomicAdd(o + 3, v * xv.w);
}

__global__ __launch_bounds__(256) void finalize_k(
    const float4* __restrict__ egoI, const float4* __restrict__ egoT,
    float4* __restrict__ out)
{
    int tid = blockIdx.x * 256 + threadIdx.x;
    int row = tid >> 5, q = tid & 31;
    if (row >= NTOT) return;
    float4 v = (q < 16) ? egoI[(size_t)row * 16 + q] : egoT[(size_t)row * 16 + (q - 16)];
    out[tid] = v;
}

// ============================================================================
extern "C" void kernel_launch(void* const* d_in, const int* in_sizes, int n_in,
                              void* d_out, int out_size, void* d_ws, size_t ws_size,
                              hipStream_t stream)
{
    const float* image_feats = (const float*)d_in[0];
    const float* text_feats  = (const float*)d_in[1];
    const float* image_pref  = (const float*)d_in[2];
    const float* text_pref   = (const float*)d_in[3];
    const float* W_img       = (const float*)d_in[4];
    const float* b_img       = (const float*)d_in[5];
    const float* W_txt       = (const float*)d_in[6];
    const float* b_txt       = (const float*)d_in[7];
    const float* adj_vals    = (const float*)d_in[8];
    const int*   adj_rows    = (const int*)d_in[9];
    const int*   adj_cols    = (const int*)d_in[10];

    float* out = (float*)d_out;
    char*  ws  = (char*)d_ws;

    const size_t OFF_X1      = 0;
    const size_t OFF_SPAIR   = 76800000;
    const size_t OFF_RSTART  = 128000000;
    const size_t OFF_CURSOR  = 128600016;
    const size_t OFF_PART    = 129200016;
    const size_t NEED        = 129201040;

    if (ws_size >= NEED) {
        float* X1     = (float*)(ws + OFF_X1);
        int2*  spair  = (int2*) (ws + OFF_SPAIR);
        int*   rstart = (int*)  (ws + OFF_RSTART);
        int*   cursor = (int*)  (ws + OFF_CURSOR);
        int*   part   = (int*)  (ws + OFF_PART);

        // ---- ego0 directly in d_out, interleaved [N][128] ----
        build_user<<<(N_USERS * 16 + 255) / 256, 256, 0, stream>>>(
            (const float4*)image_pref, (const float4*)text_pref, (float4*)out);
        float* items = out + (size_t)N_USERS * 128;
        gemm_rows16<<<(N_ITEMS + 15) / 16, 64, 0, stream>>>(image_feats, W_img, b_img,
                                                            items, N_ITEMS, 4096, 128, 1);
        gemm_rows16<<<(N_ITEMS + 15) / 16, 64, 0, stream>>>(text_feats, W_txt, b_txt,
                                                            items + 64, N_ITEMS, 384, 128, 1);

        // ---- counting sort of adjacency by row ----
        hipMemsetAsync(cursor, 0, (size_t)NTOT * sizeof(int), stream);
        hist_k<<<NNZV / 256, 256, 0, stream>>>(adj_rows, cursor);
        const int NP = (NTOT + 1023) / 1024;
        scan_block<<<NP, 256, 0, stream>>>(cursor, rstart, part, NTOT);
        scan_partials<<<1, 256, 0, stream>>>(part, NP);
        add_offsets<<<(NTOT + 255) / 256, 256, 0, stream>>>(rstart, part, NTOT);
        set_tail<<<1, 64, 0, stream>>>(rstart);
        copy4<<<(NTOT / 4 + 255) / 256, 256, 0, stream>>>(
            (const float4*)rstart, (float4*)cursor, NTOT / 4);
        scatter_k<<<NNZV / 256, 256, 0, stream>>>(adj_vals, adj_rows, adj_cols, cursor, spair);

        // ---- 2 propagation layers ----
        spmm_cols<<<NTOT / 2, 256, 0, stream>>>(spair, rstart, out, X1);
        spmm_cols<<<NTOT / 2, 256, 0, stream>>>(spair, rstart, X1, out);
        return;
    }

    // ================= fallback: round-1 atomic path =================
    float* wsf = (float*)d_ws;
    float* Ai = wsf;
    float* At = wsf + SZ;
    float* Bi = out;
    float* Bt = out + SZ;

    const int n4_pref = N_USERS * DD / 4;
    const int n4_ego  = (int)(SZ / 4);

    copy4<<<n4_pref / 256, 256, 0, stream>>>((const float4*)image_pref, (float4*)Ai, n4_pref);
    copy4<<<n4_pref / 256, 256, 0, stream>>>((const float4*)text_pref,  (float4*)At, n4_pref);

    gemm_bias<<<(N_ITEMS + 63) / 64, 256, 0, stream>>>(image_feats, W_img, b_img,
                                                       Ai + (size_t)N_USERS * DD, N_ITEMS, 4096, DD);
    gemm_bias<<<(N_ITEMS + 63) / 64, 256, 0, stream>>>(text_feats,  W_txt, b_txt,
                                                       At + (size_t)N_USERS * DD, N_ITEMS, 384, DD);
    l2norm_rows<<<(N_ITEMS + 3) / 4, 256, 0, stream>>>(Ai + (size_t)N_USERS * DD, N_ITEMS, DD);
    l2norm_rows<<<(N_ITEMS + 3) / 4, 256, 0, stream>>>(At + (size_t)N_USERS * DD, N_ITEMS, DD);

    const int spmm_blocks = (int)(((long long)NNZV * 16 + 255) / 256);

    scale4<<<(n4_ego + 255) / 256, 256, 0, stream>>>((const float4*)Ai, (float4*)Bi, n4_ego);
    spmm_atomic<<<spmm_blocks, 256, 0, stream>>>(adj_vals, adj_rows, adj_cols, Ai, Bi, NNZV);
    scale4<<<(n4_ego + 255) / 256, 256, 0, stream>>>((const float4*)At, (float4*)Bt, n4_ego);
    spmm_atomic<<<spmm_blocks, 256, 0, stream>>>(adj_vals, adj_rows, adj_cols, At, Bt, NNZV);

    scale4<<<(n4_ego + 255) / 256, 256, 0, stream>>>((const float4*)Bi, (float4*)Ai, n4_ego);
    spmm_atomic<<<spmm_blocks, 256, 0, stream>>>(adj_vals, adj_rows, adj_cols, Bi, Ai, NNZV);
    scale4<<<(n4_ego + 255) / 256, 256, 0, stream>>>((const float4*)Bt, (float4*)At, n4_ego);
    spmm_atomic<<<spmm_blocks, 256, 0, stream>>>(adj_vals, adj_rows, adj_cols, Bt, At, NNZV);

    finalize_k<<<(NTOT * 32) / 256, 256, 0, stream>>>((const float4*)Ai, (const float4*)At,
                                                      (float4*)out);
}

// Round 4
// 2153.709 us; speedup vs baseline: 2.5431x; 2.5431x over previous
//
#include <hip/hip_runtime.h>

#define N_USERS 100000
#define N_ITEMS 50000
#define NTOT    150000
#define DD      64
#define NNZV    6400000
#define ALPHA_  0.3f

static constexpr size_t SZ  = (size_t)NTOT * DD;
static constexpr size_t SZP = (size_t)50048 * 64;   // padded partial buffer (391*128 rows)

// ================= LDS-staged fp32 GEMM tile: Cp[M,64] += A[M,Krange] @ W[Krange,64] ======
// 256 threads, tile 128x64, microtile 8x4, BK=32. Writes PARTIAL sums (no bias).
#define BM 128
#define BK 32
__global__ __launch_bounds__(256) void gemm_tile(
    const float* __restrict__ A, const float* __restrict__ W,
    float* __restrict__ CpBase, int M, int K, int kchunk)
{
    __shared__ float As[BK][BM];     // [k][m] 16 KB
    __shared__ float Bs[BK][68];     // [k][n] padded   8.5 KB
    const int t  = threadIdx.x;
    const int tx = t & 15;           // col group: cols tx*4..+3
    const int ty = t >> 4;           // row group: rows ty*8..+7
    const int mblk = blockIdx.x * BM;
    const int k0beg = blockIdx.y * kchunk;
    const int k0end = k0beg + kchunk;
    float* Cp = CpBase + (size_t)blockIdx.y * SZP;

    // A-load map: thread t -> row t>>1, 16 consecutive k at offset (t&1)*16
    const int arow  = t >> 1;
    const int akoff = (t & 1) * 16;
    // W-load map: thread t -> k-row t>>3, 8 cols at (t&7)*8
    const int wk = t >> 3;
    const int wn = (t & 7) * 8;

    float acc[8][4];
    #pragma unroll
    for (int r = 0; r < 8; ++r)
        #pragma unroll
        for (int c = 0; c < 4; ++c) acc[r][c] = 0.f;

    int gm = mblk + arow; if (gm >= M) gm = M - 1;   // clamp (tail rows read row M-1)
    const float* aprow = A + (size_t)gm * K;

    for (int k0 = k0beg; k0 < k0end; k0 += BK) {
        const float* ap = aprow + k0 + akoff;
        float4 a0 = *(const float4*)(ap + 0);
        float4 a1 = *(const float4*)(ap + 4);
        float4 a2 = *(const float4*)(ap + 8);
        float4 a3 = *(const float4*)(ap + 12);
        const float* wp = W + (size_t)(k0 + wk) * DD + wn;
        float4 w0 = *(const float4*)(wp + 0);
        float4 w1 = *(const float4*)(wp + 4);

        __syncthreads();   // previous tile fully consumed
        As[akoff+ 0][arow] = a0.x; As[akoff+ 1][arow] = a0.y;
        As[akoff+ 2][arow] = a0.z; As[akoff+ 3][arow] = a0.w;
        As[akoff+ 4][arow] = a1.x; As[akoff+ 5][arow] = a1.y;
        As[akoff+ 6][arow] = a1.z; As[akoff+ 7][arow] = a1.w;
        As[akoff+ 8][arow] = a2.x; As[akoff+ 9][arow] = a2.y;
        As[akoff+10][arow] = a2.z; As[akoff+11][arow] = a2.w;
        As[akoff+12][arow] = a3.x; As[akoff+13][arow] = a3.y;
        As[akoff+14][arow] = a3.z; As[akoff+15][arow] = a3.w;
        *(float4*)&Bs[wk][wn + 0] = w0;
        *(float4*)&Bs[wk][wn + 4] = w1;
        __syncthreads();

        #pragma unroll
        for (int k = 0; k < BK; ++k) {
            const float4 af0 = *(const float4*)&As[k][ty * 8 + 0];
            const float4 af1 = *(const float4*)&As[k][ty * 8 + 4];
            const float4 wf  = *(const float4*)&Bs[k][tx * 4];
            acc[0][0] += af0.x*wf.x; acc[0][1] += af0.x*wf.y; acc[0][2] += af0.x*wf.z; acc[0][3] += af0.x*wf.w;
            acc[1][0] += af0.y*wf.x; acc[1][1] += af0.y*wf.y; acc[1][2] += af0.y*wf.z; acc[1][3] += af0.y*wf.w;
            acc[2][0] += af0.z*wf.x; acc[2][1] += af0.z*wf.y; acc[2][2] += af0.z*wf.z; acc[2][3] += af0.z*wf.w;
            acc[3][0] += af0.w*wf.x; acc[3][1] += af0.w*wf.y; acc[3][2] += af0.w*wf.z; acc[3][3] += af0.w*wf.w;
            acc[4][0] += af1.x*wf.x; acc[4][1] += af1.x*wf.y; acc[4][2] += af1.x*wf.z; acc[4][3] += af1.x*wf.w;
            acc[5][0] += af1.y*wf.x; acc[5][1] += af1.y*wf.y; acc[5][2] += af1.y*wf.z; acc[5][3] += af1.y*wf.w;
            acc[6][0] += af1.z*wf.x; acc[6][1] += af1.z*wf.y; acc[6][2] += af1.z*wf.z; acc[6][3] += af1.z*wf.w;
            acc[7][0] += af1.w*wf.x; acc[7][1] += af1.w*wf.y; acc[7][2] += af1.w*wf.z; acc[7][3] += af1.w*wf.w;
        }
    }

    #pragma unroll
    for (int r = 0; r < 8; ++r) {
        int m = mblk + ty * 8 + r;   // always < 50048 (padded buffer)
        *(float4*)(Cp + (size_t)m * DD + tx * 4) =
            make_float4(acc[r][0], acc[r][1], acc[r][2], acc[r][3]);
    }
}

// ===== epilogue: v = Cp0+Cp1(optional)+bias; L2-normalize row; store to out (ld=128) =====
__global__ __launch_bounds__(256) void epilogue_norm(
    const float* __restrict__ Cp0, const float* __restrict__ Cp1,
    const float* __restrict__ bias, float* __restrict__ outp, int nrows, int two)
{
    int row  = blockIdx.x * 4 + (threadIdx.x >> 6);
    int lane = threadIdx.x & 63;
    if (row >= nrows) return;
    float v = Cp0[(size_t)row * DD + lane] + bias[lane];
    if (two) v += Cp1[(size_t)row * DD + lane];
    float s = v * v;
    #pragma unroll
    for (int off = 32; off > 0; off >>= 1) s += __shfl_xor(s, off);
    v = v / fmaxf(sqrtf(s), 1e-12f);
    outp[(size_t)row * 128 + lane] = v;
}

// ================= interleave user prefs into X[row][0:64|64:128] ===========
__global__ __launch_bounds__(256) void build_user(const float4* __restrict__ ip,
                                                  const float4* __restrict__ tp,
                                                  float4* __restrict__ X)
{
    int i = blockIdx.x * 256 + threadIdx.x;
    if (i >= N_USERS * 16) return;
    int row = i >> 4, q = i & 15;
    X[(size_t)row * 32 + q]      = ip[i];
    X[(size_t)row * 32 + 16 + q] = tp[i];
}

// ================= counting sort by row =====================================
__global__ __launch_bounds__(256) void hist_k(const int* __restrict__ rows, int* __restrict__ hist)
{
    int i = blockIdx.x * 256 + threadIdx.x;
    if (i < NNZV) atomicAdd(&hist[rows[i]], 1);
}

__global__ __launch_bounds__(256) void scan_block(const int* __restrict__ in, int* __restrict__ out,
                                                  int* __restrict__ partials, int n)
{
    __shared__ int sh[256];
    int t = threadIdx.x;
    int base = blockIdx.x * 1024 + t * 4;
    int v0 = 0, v1 = 0, v2 = 0, v3 = 0;
    if (base + 3 < n) { int4 x = *(const int4*)(in + base); v0 = x.x; v1 = x.y; v2 = x.z; v3 = x.w; }
    else {
        if (base     < n) v0 = in[base];
        if (base + 1 < n) v1 = in[base + 1];
        if (base + 2 < n) v2 = in[base + 2];
        if (base + 3 < n) v3 = in[base + 3];
    }
    int tsum = v0 + v1 + v2 + v3;
    sh[t] = tsum;
    __syncthreads();
    for (int off = 1; off < 256; off <<= 1) {
        int x = 0;
        if (t >= off) x = sh[t - off];
        __syncthreads();
        sh[t] += x;
        __syncthreads();
    }
    int texcl = sh[t] - tsum;
    if (t == 255) partials[blockIdx.x] = sh[255];
    int e0 = texcl, e1 = e0 + v0, e2 = e1 + v1, e3 = e2 + v2;
    if (base + 3 < n) { *(int4*)(out + base) = make_int4(e0, e1, e2, e3); }
    else {
        if (base     < n) out[base]     = e0;
        if (base + 1 < n) out[base + 1] = e1;
        if (base + 2 < n) out[base + 2] = e2;
        if (base + 3 < n) out[base + 3] = e3;
    }
}

__global__ __launch_bounds__(256) void scan_partials(int* __restrict__ p, int np)
{
    __shared__ int sh[256];
    int t = threadIdx.x;
    int v = (t < np) ? p[t] : 0;
    sh[t] = v;
    __syncthreads();
    for (int off = 1; off < 256; off <<= 1) {
        int x = 0;
        if (t >= off) x = sh[t - off];
        __syncthreads();
        sh[t] += x;
        __syncthreads();
    }
    if (t < np) p[t] = sh[t] - v;
}

__global__ __launch_bounds__(256) void add_offsets(int* __restrict__ out,
                                                   const int* __restrict__ partials, int n)
{
    int i = blockIdx.x * 256 + threadIdx.x;
    if (i < n) out[i] += partials[i >> 10];
}

__global__ void set_tail(int* __restrict__ rstart)
{
    if (threadIdx.x == 0 && blockIdx.x == 0) rstart[NTOT] = NNZV;
}

__global__ __launch_bounds__(256) void copy4(const float4* __restrict__ src,
                                             float4* __restrict__ dst, int n4)
{
    int i = blockIdx.x * 256 + threadIdx.x;
    if (i < n4) dst[i] = src[i];
}

__global__ __launch_bounds__(256) void scatter_k(
    const float* __restrict__ vals, const int* __restrict__ rows, const int* __restrict__ cols,
    int* __restrict__ cursor, int2* __restrict__ spair)
{
    int i = blockIdx.x * 256 + threadIdx.x;
    if (i >= NNZV) return;
    int r = rows[i];
    int p = atomicAdd(&cursor[r], 1);
    spair[p] = make_int2(__float_as_int(vals[i]), cols[i]);
}

// ================= column-parallel per-row SpMM (unroll 8) ==================
__global__ __launch_bounds__(256) void spmm_cols(
    const int2* __restrict__ spair, const int* __restrict__ rstart,
    const float* __restrict__ Xin, float* __restrict__ Xout)
{
    int row = (blockIdx.x << 1) + (threadIdx.x >> 7);
    int c   = threadIdx.x & 127;
    if (row >= NTOT) return;
    int beg = rstart[row];
    int end = rstart[row + 1];
    float a = 0.f, b = 0.f;
    int j = beg;
    for (; j + 8 <= end; j += 8) {
        int2 p0 = spair[j];     int2 p1 = spair[j + 1];
        int2 p2 = spair[j + 2]; int2 p3 = spair[j + 3];
        int2 p4 = spair[j + 4]; int2 p5 = spair[j + 5];
        int2 p6 = spair[j + 6]; int2 p7 = spair[j + 7];
        float x0 = Xin[(size_t)p0.y * 128 + c];
        float x1 = Xin[(size_t)p1.y * 128 + c];
        float x2 = Xin[(size_t)p2.y * 128 + c];
        float x3 = Xin[(size_t)p3.y * 128 + c];
        float x4 = Xin[(size_t)p4.y * 128 + c];
        float x5 = Xin[(size_t)p5.y * 128 + c];
        float x6 = Xin[(size_t)p6.y * 128 + c];
        float x7 = Xin[(size_t)p7.y * 128 + c];
        a += __int_as_float(p0.x) * x0;  b += __int_as_float(p1.x) * x1;
        a += __int_as_float(p2.x) * x2;  b += __int_as_float(p3.x) * x3;
        a += __int_as_float(p4.x) * x4;  b += __int_as_float(p5.x) * x5;
        a += __int_as_float(p6.x) * x6;  b += __int_as_float(p7.x) * x7;
    }
    for (; j < end; ++j) {
        int2 p = spair[j];
        a += __int_as_float(p.x) * Xin[(size_t)p.y * 128 + c];
    }
    size_t o = (size_t)row * 128 + c;
    Xout[o] = a + b + ALPHA_ * Xin[o];
}

// ================= fallback (round-1) kernels ===============================
__global__ __launch_bounds__(256) void gemm_bias(
    const float* __restrict__ A, const float* __restrict__ W,
    const float* __restrict__ bias, float* __restrict__ C, int M, int K, int ldc)
{
    __shared__ float As2[16][64];
    __shared__ float Bs2[16][64];
    const int t  = threadIdx.x;
    const int tx = t & 15, ty = t >> 4;
    const int lr = t >> 2;
    const int lk = (t & 3) << 2;
    const int brow = t >> 4;
    const int bc   = (t & 15) << 2;
    const int block_row = blockIdx.x << 6;

    float acc[4][4] = {{0.f,0.f,0.f,0.f},{0.f,0.f,0.f,0.f},{0.f,0.f,0.f,0.f},{0.f,0.f,0.f,0.f}};
    const int grow = block_row + lr;
    const bool arow_ok = (grow < M);
    const float* Aptr = A + (size_t)grow * K;

    for (int k0 = 0; k0 < K; k0 += 16) {
        float4 av = make_float4(0.f, 0.f, 0.f, 0.f);
        if (arow_ok) av = *(const float4*)(Aptr + k0 + lk);
        As2[lk+0][lr] = av.x; As2[lk+1][lr] = av.y; As2[lk+2][lr] = av.z; As2[lk+3][lr] = av.w;
        *(float4*)&Bs2[brow][bc] = *(const float4*)(W + (size_t)(k0 + brow) * DD + bc);
        __syncthreads();
        #pragma unroll
        for (int k = 0; k < 16; ++k) {
            float4 a = *(const float4*)&As2[k][ty << 2];
            float4 b = *(const float4*)&Bs2[k][tx << 2];
            acc[0][0] += a.x*b.x; acc[0][1] += a.x*b.y; acc[0][2] += a.x*b.z; acc[0][3] += a.x*b.w;
            acc[1][0] += a.y*b.x; acc[1][1] += a.y*b.y; acc[1][2] += a.y*b.z; acc[1][3] += a.y*b.w;
            acc[2][0] += a.z*b.x; acc[2][1] += a.z*b.y; acc[2][2] += a.z*b.z; acc[2][3] += a.z*b.w;
            acc[3][0] += a.w*b.x; acc[3][1] += a.w*b.y; acc[3][2] += a.w*b.z; acc[3][3] += a.w*b.w;
        }
        __syncthreads();
    }
    const float4 bv = *(const float4*)(bias + (tx << 2));
    #pragma unroll
    for (int i = 0; i < 4; ++i) {
        int row = block_row + (ty << 2) + i;
        if (row < M) {
            float4 o = make_float4(acc[i][0] + bv.x, acc[i][1] + bv.y,
                                   acc[i][2] + bv.z, acc[i][3] + bv.w);
            *(float4*)(C + (size_t)row * ldc + (tx << 2)) = o;
        }
    }
}

__global__ __launch_bounds__(256) void l2norm_rows(float* __restrict__ x, int nrows, int ld)
{
    int row  = blockIdx.x * 4 + (threadIdx.x >> 6);
    int lane = threadIdx.x & 63;
    if (row >= nrows) return;
    float v = x[(size_t)row * ld + lane];
    float s = v * v;
    #pragma unroll
    for (int off = 32; off > 0; off >>= 1) s += __shfl_xor(s, off);
    float n = sqrtf(s);
    x[(size_t)row * ld + lane] = v / fmaxf(n, 1e-12f);
}

__global__ __launch_bounds__(256) void scale4(const float4* __restrict__ src,
                                              float4* __restrict__ dst, int n4)
{
    int i = blockIdx.x * 256 + threadIdx.x;
    if (i < n4) {
        float4 v = src[i];
        dst[i] = make_float4(ALPHA_*v.x, ALPHA_*v.y, ALPHA_*v.z, ALPHA_*v.w);
    }
}

__global__ __launch_bounds__(256) void spmm_atomic(
    const float* __restrict__ vals, const int* __restrict__ rows,
    const int* __restrict__ cols, const float* __restrict__ x,
    float* __restrict__ out, int nnz)
{
    long long tid = (long long)blockIdx.x * 256 + threadIdx.x;
    int g = (int)(tid >> 4);
    if (g >= nnz) return;
    int lane = (int)(tid & 15);
    float v = vals[g];
    int r = rows[g], c = cols[g];
    float4 xv = *((const float4*)(x + (size_t)c * DD) + lane);
    float* o = out + (size_t)r * DD + (lane << 2);
    atomicAdd(o + 0, v * xv.x);
    atomicAdd(o + 1, v * xv.y);
    atomicAdd(o + 2, v * xv.z);
    atomicAdd(o + 3, v * xv.w);
}

__global__ __launch_bounds__(256) void finalize_k(
    const float4* __restrict__ egoI, const float4* __restrict__ egoT,
    float4* __restrict__ out)
{
    int tid = blockIdx.x * 256 + threadIdx.x;
    int row = tid >> 5, q = tid & 31;
    if (row >= NTOT) return;
    float4 v = (q < 16) ? egoI[(size_t)row * 16 + q] : egoT[(size_t)row * 16 + (q - 16)];
    out[tid] = v;
}

// ============================================================================
extern "C" void kernel_launch(void* const* d_in, const int* in_sizes, int n_in,
                              void* d_out, int out_size, void* d_ws, size_t ws_size,
                              hipStream_t stream)
{
    const float* image_feats = (const float*)d_in[0];
    const float* text_feats  = (const float*)d_in[1];
    const float* image_pref  = (const float*)d_in[2];
    const float* text_pref   = (const float*)d_in[3];
    const float* W_img       = (const float*)d_in[4];
    const float* b_img       = (const float*)d_in[5];
    const float* W_txt       = (const float*)d_in[6];
    const float* b_txt       = (const float*)d_in[7];
    const float* adj_vals    = (const float*)d_in[8];
    const int*   adj_rows    = (const int*)d_in[9];
    const int*   adj_cols    = (const int*)d_in[10];

    float* out = (float*)d_out;
    char*  ws  = (char*)d_ws;

    const size_t OFF_X1      = 0;
    const size_t OFF_SPAIR   = 76800000;
    const size_t OFF_RSTART  = 128000000;
    const size_t OFF_CURSOR  = 128600016;
    const size_t OFF_PART    = 129200016;
    const size_t NEED        = 129201040;

    if (ws_size >= NEED) {
        float* X1     = (float*)(ws + OFF_X1);
        int2*  spair  = (int2*) (ws + OFF_SPAIR);
        int*   rstart = (int*)  (ws + OFF_RSTART);
        int*   cursor = (int*)  (ws + OFF_CURSOR);
        int*   part   = (int*)  (ws + OFF_PART);

        // partial GEMM buffers alias X1 (X1 not live until first spmm)
        float* Cp0 = X1;                  // image K-half 0
        float* Cp2 = X1 + 2 * SZP;        // text
        float* items = out + (size_t)N_USERS * 128;

        // ---- ego0: users interleaved into d_out ----
        build_user<<<(N_USERS * 16 + 255) / 256, 256, 0, stream>>>(
            (const float4*)image_pref, (const float4*)text_pref, (float4*)out);

        // ---- item GEMMs (partial sums), then fused add+bias+norm epilogues ----
        dim3 gimg((N_ITEMS + BM - 1) / BM, 2);
        gemm_tile<<<gimg, 256, 0, stream>>>(image_feats, W_img, Cp0, N_ITEMS, 4096, 2048);
        dim3 gtxt((N_ITEMS + BM - 1) / BM, 1);
        gemm_tile<<<gtxt, 256, 0, stream>>>(text_feats, W_txt, Cp2, N_ITEMS, 384, 384);
        epilogue_norm<<<(N_ITEMS + 3) / 4, 256, 0, stream>>>(Cp0, Cp0 + SZP, b_img,
                                                             items, N_ITEMS, 1);
        epilogue_norm<<<(N_ITEMS + 3) / 4, 256, 0, stream>>>(Cp2, Cp2, b_txt,
                                                             items + 64, N_ITEMS, 0);

        // ---- counting sort of adjacency by row ----
        hipMemsetAsync(cursor, 0, (size_t)NTOT * sizeof(int), stream);
        hist_k<<<NNZV / 256, 256, 0, stream>>>(adj_rows, cursor);
        const int NP = (NTOT + 1023) / 1024;
        scan_block<<<NP, 256, 0, stream>>>(cursor, rstart, part, NTOT);
        scan_partials<<<1, 256, 0, stream>>>(part, NP);
        add_offsets<<<(NTOT + 255) / 256, 256, 0, stream>>>(rstart, part, NTOT);
        set_tail<<<1, 64, 0, stream>>>(rstart);
        copy4<<<(NTOT / 4 + 255) / 256, 256, 0, stream>>>(
            (const float4*)rstart, (float4*)cursor, NTOT / 4);
        scatter_k<<<NNZV / 256, 256, 0, stream>>>(adj_vals, adj_rows, adj_cols, cursor, spair);

        // ---- 2 propagation layers ----
        spmm_cols<<<NTOT / 2, 256, 0, stream>>>(spair, rstart, out, X1);
        spmm_cols<<<NTOT / 2, 256, 0, stream>>>(spair, rstart, X1, out);
        return;
    }

    // ================= fallback: round-1 atomic path =================
    float* wsf = (float*)d_ws;
    float* Ai = wsf;
    float* At = wsf + SZ;
    float* Bi = out;
    float* Bt = out + SZ;

    const int n4_pref = N_USERS * DD / 4;
    const int n4_ego  = (int)(SZ / 4);

    copy4<<<n4_pref / 256, 256, 0, stream>>>((const float4*)image_pref, (float4*)Ai, n4_pref);
    copy4<<<n4_pref / 256, 256, 0, stream>>>((const float4*)text_pref,  (float4*)At, n4_pref);

    gemm_bias<<<(N_ITEMS + 63) / 64, 256, 0, stream>>>(image_feats, W_img, b_img,
                                                       Ai + (size_t)N_USERS * DD, N_ITEMS, 4096, DD);
    gemm_bias<<<(N_ITEMS + 63) / 64, 256, 0, stream>>>(text_feats,  W_txt, b_txt,
                                                       At + (size_t)N_USERS * DD, N_ITEMS, 384, DD);
    l2norm_rows<<<(N_ITEMS + 3) / 4, 256, 0, stream>>>(Ai + (size_t)N_USERS * DD, N_ITEMS, DD);
    l2norm_rows<<<(N_ITEMS + 3) / 4, 256, 0, stream>>>(At + (size_t)N_USERS * DD, N_ITEMS, DD);

    const int spmm_blocks = (int)(((long long)NNZV * 16 + 255) / 256);

    scale4<<<(n4_ego + 255) / 256, 256, 0, stream>>>((const float4*)Ai, (float4*)Bi, n4_ego);
    spmm_atomic<<<spmm_blocks, 256, 0, stream>>>(adj_vals, adj_rows, adj_cols, Ai, Bi, NNZV);
    scale4<<<(n4_ego + 255) / 256, 256, 0, stream>>>((const float4*)At, (float4*)Bt, n4_ego);
    spmm_atomic<<<spmm_blocks, 256, 0, stream>>>(adj_vals, adj_rows, adj_cols, At, Bt, NNZV);

    scale4<<<(n4_ego + 255) / 256, 256, 0, stream>>>((const float4*)Bi, (float4*)Ai, n4_ego);
    spmm_atomic<<<spmm_blocks, 256, 0, stream>>>(adj_vals, adj_rows, adj_cols, Bi, Ai, NNZV);
    scale4<<<(n4_ego + 255) / 256, 256, 0, stream>>>((const float4*)Bt, (float4*)At, n4_ego);
    spmm_atomic<<<spmm_blocks, 256, 0, stream>>>(adj_vals, adj_rows, adj_cols, Bt, At, NNZV);

    finalize_k<<<(NTOT * 32) / 256, 256, 0, stream>>>((const float4*)Ai, (const float4*)At,
                                                      (float4*)out);
}

// Round 5
// 1766.709 us; speedup vs baseline: 3.1002x; 1.2191x over previous
//
#include <hip/hip_runtime.h>

#define N_USERS 100000
#define N_ITEMS 50000
#define NTOT    150000
#define DD      64
#define NNZV    6400000
#define ALPHA_  0.3f

#define BSHIFT  9
#define NBUCK   293        // ceil(150000 / 512)
#define CH      16384      // nnz chunk per pass-1 block
#define NCH     391        // ceil(NNZV / CH)

static constexpr size_t SZ  = (size_t)NTOT * DD;
static constexpr size_t SZP = (size_t)50048 * 64;   // padded GEMM partial buffer

// ================= LDS-staged fp32 GEMM tile: 128x64, microtile 8x4, BK=32 ======
#define BM 128
#define BK 32
__global__ __launch_bounds__(256) void gemm_tile(
    const float* __restrict__ A, const float* __restrict__ W,
    float* __restrict__ CpBase, int M, int K, int kchunk)
{
    __shared__ float As[BK][BM];
    __shared__ float Bs[BK][68];
    const int t  = threadIdx.x;
    const int tx = t & 15;
    const int ty = t >> 4;
    const int mblk = blockIdx.x * BM;
    const int k0beg = blockIdx.y * kchunk;
    const int k0end = k0beg + kchunk;
    float* Cp = CpBase + (size_t)blockIdx.y * SZP;

    const int arow  = t >> 1;
    const int akoff = (t & 1) * 16;
    const int wk = t >> 3;
    const int wn = (t & 7) * 8;

    float acc[8][4];
    #pragma unroll
    for (int r = 0; r < 8; ++r)
        #pragma unroll
        for (int c = 0; c < 4; ++c) acc[r][c] = 0.f;

    int gm = mblk + arow; if (gm >= M) gm = M - 1;
    const float* aprow = A + (size_t)gm * K;

    for (int k0 = k0beg; k0 < k0end; k0 += BK) {
        const float* ap = aprow + k0 + akoff;
        float4 a0 = *(const float4*)(ap + 0);
        float4 a1 = *(const float4*)(ap + 4);
        float4 a2 = *(const float4*)(ap + 8);
        float4 a3 = *(const float4*)(ap + 12);
        const float* wp = W + (size_t)(k0 + wk) * DD + wn;
        float4 w0 = *(const float4*)(wp + 0);
        float4 w1 = *(const float4*)(wp + 4);

        __syncthreads();
        As[akoff+ 0][arow] = a0.x; As[akoff+ 1][arow] = a0.y;
        As[akoff+ 2][arow] = a0.z; As[akoff+ 3][arow] = a0.w;
        As[akoff+ 4][arow] = a1.x; As[akoff+ 5][arow] = a1.y;
        As[akoff+ 6][arow] = a1.z; As[akoff+ 7][arow] = a1.w;
        As[akoff+ 8][arow] = a2.x; As[akoff+ 9][arow] = a2.y;
        As[akoff+10][arow] = a2.z; As[akoff+11][arow] = a2.w;
        As[akoff+12][arow] = a3.x; As[akoff+13][arow] = a3.y;
        As[akoff+14][arow] = a3.z; As[akoff+15][arow] = a3.w;
        *(float4*)&Bs[wk][wn + 0] = w0;
        *(float4*)&Bs[wk][wn + 4] = w1;
        __syncthreads();

        #pragma unroll
        for (int k = 0; k < BK; ++k) {
            const float4 af0 = *(const float4*)&As[k][ty * 8 + 0];
            const float4 af1 = *(const float4*)&As[k][ty * 8 + 4];
            const float4 wf  = *(const float4*)&Bs[k][tx * 4];
            acc[0][0] += af0.x*wf.x; acc[0][1] += af0.x*wf.y; acc[0][2] += af0.x*wf.z; acc[0][3] += af0.x*wf.w;
            acc[1][0] += af0.y*wf.x; acc[1][1] += af0.y*wf.y; acc[1][2] += af0.y*wf.z; acc[1][3] += af0.y*wf.w;
            acc[2][0] += af0.z*wf.x; acc[2][1] += af0.z*wf.y; acc[2][2] += af0.z*wf.z; acc[2][3] += af0.z*wf.w;
            acc[3][0] += af0.w*wf.x; acc[3][1] += af0.w*wf.y; acc[3][2] += af0.w*wf.z; acc[3][3] += af0.w*wf.w;
            acc[4][0] += af1.x*wf.x; acc[4][1] += af1.x*wf.y; acc[4][2] += af1.x*wf.z; acc[4][3] += af1.x*wf.w;
            acc[5][0] += af1.y*wf.x; acc[5][1] += af1.y*wf.y; acc[5][2] += af1.y*wf.z; acc[5][3] += af1.y*wf.w;
            acc[6][0] += af1.z*wf.x; acc[6][1] += af1.z*wf.y; acc[6][2] += af1.z*wf.z; acc[6][3] += af1.z*wf.w;
            acc[7][0] += af1.w*wf.x; acc[7][1] += af1.w*wf.y; acc[7][2] += af1.w*wf.z; acc[7][3] += af1.w*wf.w;
        }
    }

    #pragma unroll
    for (int r = 0; r < 8; ++r) {
        int m = mblk + ty * 8 + r;
        *(float4*)(Cp + (size_t)m * DD + tx * 4) =
            make_float4(acc[r][0], acc[r][1], acc[r][2], acc[r][3]);
    }
}

// ===== epilogue: v = Cp0+Cp1(optional)+bias; L2-normalize row; store (ld=128) =====
__global__ __launch_bounds__(256) void epilogue_norm(
    const float* __restrict__ Cp0, const float* __restrict__ Cp1,
    const float* __restrict__ bias, float* __restrict__ outp, int nrows, int two)
{
    int row  = blockIdx.x * 4 + (threadIdx.x >> 6);
    int lane = threadIdx.x & 63;
    if (row >= nrows) return;
    float v = Cp0[(size_t)row * DD + lane] + bias[lane];
    if (two) v += Cp1[(size_t)row * DD + lane];
    float s = v * v;
    #pragma unroll
    for (int off = 32; off > 0; off >>= 1) s += __shfl_xor(s, off);
    v = v / fmaxf(sqrtf(s), 1e-12f);
    outp[(size_t)row * 128 + lane] = v;
}

// ================= interleave user prefs into X[row][0:64|64:128] ===========
__global__ __launch_bounds__(256) void build_user(const float4* __restrict__ ip,
                                                  const float4* __restrict__ tp,
                                                  float4* __restrict__ X)
{
    int i = blockIdx.x * 256 + threadIdx.x;
    if (i >= N_USERS * 16) return;
    int row = i >> 4, q = i & 15;
    X[(size_t)row * 32 + q]      = ip[i];
    X[(size_t)row * 32 + 16 + q] = tp[i];
}

// ================= bucketed 2-pass row sort =================================
// bucket = row >> 9 (293 buckets of <=512 rows, ~262KB of pairs each)

// per-block LDS bucket histogram -> global bucket hist (293 atomics/block)
__global__ __launch_bounds__(256) void bucket_cnt(const int* __restrict__ rows,
                                                  int* __restrict__ gbhist)
{
    __shared__ int cnt[NBUCK];
    int t = threadIdx.x;
    for (int i = t; i < NBUCK; i += 256) cnt[i] = 0;
    __syncthreads();
    int beg = blockIdx.x * CH;
    int end = beg + CH; if (end > NNZV) end = NNZV;
    for (int i = beg + t; i < end; i += 256)
        atomicAdd(&cnt[rows[i] >> BSHIFT], 1);
    __syncthreads();
    for (int i = t; i < NBUCK; i += 256)
        if (cnt[i]) atomicAdd(&gbhist[i], cnt[i]);
}

// single-block exclusive scan of 293 bucket counts -> gbstart, gbcur
__global__ __launch_bounds__(512) void scan_nbuck(const int* __restrict__ gbhist,
                                                  int* __restrict__ gbstart,
                                                  int* __restrict__ gbcur)
{
    __shared__ int sh[512];
    int t = threadIdx.x;
    int v = (t < NBUCK) ? gbhist[t] : 0;
    sh[t] = v;
    __syncthreads();
    for (int off = 1; off < 512; off <<= 1) {
        int x = (t >= off) ? sh[t - off] : 0;
        __syncthreads();
        sh[t] += x;
        __syncthreads();
    }
    if (t < NBUCK) {
        int e = sh[t] - v;
        gbstart[t] = e;
        gbcur[t]   = e;
    }
}

// pass 1: two-phase block binning into bucket-grouped (ptmp, rtmp)
__global__ __launch_bounds__(256) void sort_pass1(
    const float* __restrict__ vals, const int* __restrict__ rows,
    const int* __restrict__ cols, int* __restrict__ gbcur,
    int2* __restrict__ ptmp, int* __restrict__ rtmp)
{
    __shared__ int cnt[NBUCK];
    __shared__ int base[NBUCK];
    int t = threadIdx.x;
    int beg = blockIdx.x * CH;
    int end = beg + CH; if (end > NNZV) end = NNZV;

    for (int i = t; i < NBUCK; i += 256) cnt[i] = 0;
    __syncthreads();
    for (int i = beg + t; i < end; i += 256)
        atomicAdd(&cnt[rows[i] >> BSHIFT], 1);
    __syncthreads();
    for (int i = t; i < NBUCK; i += 256) {
        int c = cnt[i];
        base[i] = c ? atomicAdd(&gbcur[i], c) : 0;
    }
    __syncthreads();
    for (int i = t; i < NBUCK; i += 256) cnt[i] = 0;
    __syncthreads();
    for (int i = beg + t; i < end; i += 256) {
        int r = rows[i];
        int b = r >> BSHIFT;
        int rank = atomicAdd(&cnt[b], 1);
        int p = base[b] + rank;
        ptmp[p] = make_int2(__float_as_int(vals[i]), cols[i]);
        rtmp[p] = r;
    }
}

// pass 2: one block owns one bucket. LDS row-count + scan (emits rstart),
// then LDS-cursor scatter confined to the bucket's own output region.
__global__ __launch_bounds__(256) void sort_pass2(
    const int2* __restrict__ ptmp, const int* __restrict__ rtmp,
    const int* __restrict__ gbstart, int2* __restrict__ spair,
    int* __restrict__ rstart)
{
    __shared__ int rcnt[512];
    __shared__ int cur[512];
    __shared__ int s2[256];
    const int b = blockIdx.x;
    const int t = threadIdx.x;
    const int rbase  = b << BSHIFT;
    const int bstart = gbstart[b];
    const int bend   = (b == NBUCK - 1) ? NNZV : gbstart[b + 1];

    rcnt[t] = 0; rcnt[t + 256] = 0;
    __syncthreads();
    for (int i = bstart + t; i < bend; i += 256)
        atomicAdd(&rcnt[rtmp[i] - rbase], 1);
    __syncthreads();

    // exclusive scan over 512 row counts (pairwise + Hillis-Steele on 256)
    int a0 = rcnt[2 * t], a1 = rcnt[2 * t + 1];
    s2[t] = a0 + a1;
    __syncthreads();
    for (int off = 1; off < 256; off <<= 1) {
        int x = (t >= off) ? s2[t - off] : 0;
        __syncthreads();
        s2[t] += x;
        __syncthreads();
    }
    int epair = s2[t] - (a0 + a1);
    int c0 = bstart + epair;
    int c1 = c0 + a0;
    cur[2 * t]     = c0;
    cur[2 * t + 1] = c1;
    int r0 = rbase + 2 * t;
    if (r0 < NTOT)     rstart[r0]     = c0;
    if (r0 + 1 < NTOT) rstart[r0 + 1] = c1;
    __syncthreads();

    for (int i = bstart + t; i < bend; i += 256) {
        int r = rtmp[i];
        int p = atomicAdd(&cur[r - rbase], 1);
        spair[p] = ptmp[i];
    }
}

__global__ void set_tail(int* __restrict__ rstart)
{
    if (threadIdx.x == 0 && blockIdx.x == 0) rstart[NTOT] = NNZV;
}

// ================= column-parallel per-row SpMM (unroll 8) ==================
__global__ __launch_bounds__(256) void spmm_cols(
    const int2* __restrict__ spair, const int* __restrict__ rstart,
    const float* __restrict__ Xin, float* __restrict__ Xout)
{
    int row = (blockIdx.x << 1) + (threadIdx.x >> 7);
    int c   = threadIdx.x & 127;
    if (row >= NTOT) return;
    int beg = rstart[row];
    int end = rstart[row + 1];
    float a = 0.f, b = 0.f;
    int j = beg;
    for (; j + 8 <= end; j += 8) {
        int2 p0 = spair[j];     int2 p1 = spair[j + 1];
        int2 p2 = spair[j + 2]; int2 p3 = spair[j + 3];
        int2 p4 = spair[j + 4]; int2 p5 = spair[j + 5];
        int2 p6 = spair[j + 6]; int2 p7 = spair[j + 7];
        float x0 = Xin[(size_t)p0.y * 128 + c];
        float x1 = Xin[(size_t)p1.y * 128 + c];
        float x2 = Xin[(size_t)p2.y * 128 + c];
        float x3 = Xin[(size_t)p3.y * 128 + c];
        float x4 = Xin[(size_t)p4.y * 128 + c];
        float x5 = Xin[(size_t)p5.y * 128 + c];
        float x6 = Xin[(size_t)p6.y * 128 + c];
        float x7 = Xin[(size_t)p7.y * 128 + c];
        a += __int_as_float(p0.x) * x0;  b += __int_as_float(p1.x) * x1;
        a += __int_as_float(p2.x) * x2;  b += __int_as_float(p3.x) * x3;
        a += __int_as_float(p4.x) * x4;  b += __int_as_float(p5.x) * x5;
        a += __int_as_float(p6.x) * x6;  b += __int_as_float(p7.x) * x7;
    }
    for (; j < end; ++j) {
        int2 p = spair[j];
        a += __int_as_float(p.x) * Xin[(size_t)p.y * 128 + c];
    }
    size_t o = (size_t)row * 128 + c;
    Xout[o] = a + b + ALPHA_ * Xin[o];
}

// ================= fallback (round-1) kernels ===============================
__global__ __launch_bounds__(256) void copy4(const float4* __restrict__ src,
                                             float4* __restrict__ dst, int n4)
{
    int i = blockIdx.x * 256 + threadIdx.x;
    if (i < n4) dst[i] = src[i];
}

__global__ __launch_bounds__(256) void gemm_bias(
    const float* __restrict__ A, const float* __restrict__ W,
    const float* __restrict__ bias, float* __restrict__ C, int M, int K, int ldc)
{
    __shared__ float As2[16][64];
    __shared__ float Bs2[16][64];
    const int t  = threadIdx.x;
    const int tx = t & 15, ty = t >> 4;
    const int lr = t >> 2;
    const int lk = (t & 3) << 2;
    const int brow = t >> 4;
    const int bc   = (t & 15) << 2;
    const int block_row = blockIdx.x << 6;

    float acc[4][4] = {{0.f,0.f,0.f,0.f},{0.f,0.f,0.f,0.f},{0.f,0.f,0.f,0.f},{0.f,0.f,0.f,0.f}};
    const int grow = block_row + lr;
    const bool arow_ok = (grow < M);
    const float* Aptr = A + (size_t)grow * K;

    for (int k0 = 0; k0 < K; k0 += 16) {
        float4 av = make_float4(0.f, 0.f, 0.f, 0.f);
        if (arow_ok) av = *(const float4*)(Aptr + k0 + lk);
        As2[lk+0][lr] = av.x; As2[lk+1][lr] = av.y; As2[lk+2][lr] = av.z; As2[lk+3][lr] = av.w;
        *(float4*)&Bs2[brow][bc] = *(const float4*)(W + (size_t)(k0 + brow) * DD + bc);
        __syncthreads();
        #pragma unroll
        for (int k = 0; k < 16; ++k) {
            float4 a = *(const float4*)&As2[k][ty << 2];
            float4 b = *(const float4*)&Bs2[k][tx << 2];
            acc[0][0] += a.x*b.x; acc[0][1] += a.x*b.y; acc[0][2] += a.x*b.z; acc[0][3] += a.x*b.w;
            acc[1][0] += a.y*b.x; acc[1][1] += a.y*b.y; acc[1][2] += a.y*b.z; acc[1][3] += a.y*b.w;
            acc[2][0] += a.z*b.x; acc[2][1] += a.z*b.y; acc[2][2] += a.z*b.z; acc[2][3] += a.z*b.w;
            acc[3][0] += a.w*b.x; acc[3][1] += a.w*b.y; acc[3][2] += a.w*b.z; acc[3][3] += a.w*b.w;
        }
        __syncthreads();
    }
    const float4 bv = *(const float4*)(bias + (tx << 2));
    #pragma unroll
    for (int i = 0; i < 4; ++i) {
        int row = block_row + (ty << 2) + i;
        if (row < M) {
            float4 o = make_float4(acc[i][0] + bv.x, acc[i][1] + bv.y,
                                   acc[i][2] + bv.z, acc[i][3] + bv.w);
            *(float4*)(C + (size_t)row * ldc + (tx << 2)) = o;
        }
    }
}

__global__ __launch_bounds__(256) void l2norm_rows(float* __restrict__ x, int nrows, int ld)
{
    int row  = blockIdx.x * 4 + (threadIdx.x >> 6);
    int lane = threadIdx.x & 63;
    if (row >= nrows) return;
    float v = x[(size_t)row * ld + lane];
    float s = v * v;
    #pragma unroll
    for (int off = 32; off > 0; off >>= 1) s += __shfl_xor(s, off);
    float n = sqrtf(s);
    x[(size_t)row * ld + lane] = v / fmaxf(n, 1e-12f);
}

__global__ __launch_bounds__(256) void scale4(const float4* __restrict__ src,
                                              float4* __restrict__ dst, int n4)
{
    int i = blockIdx.x * 256 + threadIdx.x;
    if (i < n4) {
        float4 v = src[i];
        dst[i] = make_float4(ALPHA_*v.x, ALPHA_*v.y, ALPHA_*v.z, ALPHA_*v.w);
    }
}

__global__ __launch_bounds__(256) void spmm_atomic(
    const float* __restrict__ vals, const int* __restrict__ rows,
    const int* __restrict__ cols, const float* __restrict__ x,
    float* __restrict__ out, int nnz)
{
    long long tid = (long long)blockIdx.x * 256 + threadIdx.x;
    int g = (int)(tid >> 4);
    if (g >= nnz) return;
    int lane = (int)(tid & 15);
    float v = vals[g];
    int r = rows[g], c = cols[g];
    float4 xv = *((const float4*)(x + (size_t)c * DD) + lane);
    float* o = out + (size_t)r * DD + (lane << 2);
    atomicAdd(o + 0, v * xv.x);
    atomicAdd(o + 1, v * xv.y);
    atomicAdd(o + 2, v * xv.z);
    atomicAdd(o + 3, v * xv.w);
}

__global__ __launch_bounds__(256) void finalize_k(
    const float4* __restrict__ egoI, const float4* __restrict__ egoT,
    float4* __restrict__ out)
{
    int tid = blockIdx.x * 256 + threadIdx.x;
    int row = tid >> 5, q = tid & 31;
    if (row >= NTOT) return;
    float4 v = (q < 16) ? egoI[(size_t)row * 16 + q] : egoT[(size_t)row * 16 + (q - 16)];
    out[tid] = v;
}

// ============================================================================
extern "C" void kernel_launch(void* const* d_in, const int* in_sizes, int n_in,
                              void* d_out, int out_size, void* d_ws, size_t ws_size,
                              hipStream_t stream)
{
    const float* image_feats = (const float*)d_in[0];
    const float* text_feats  = (const float*)d_in[1];
    const float* image_pref  = (const float*)d_in[2];
    const float* text_pref   = (const float*)d_in[3];
    const float* W_img       = (const float*)d_in[4];
    const float* b_img       = (const float*)d_in[5];
    const float* W_txt       = (const float*)d_in[6];
    const float* b_txt       = (const float*)d_in[7];
    const float* adj_vals    = (const float*)d_in[8];
    const int*   adj_rows    = (const int*)d_in[9];
    const int*   adj_cols    = (const int*)d_in[10];

    float* out = (float*)d_out;
    char*  ws  = (char*)d_ws;

    const size_t OFF_X1      = 0;           // 76,800,000 B (X1; also hosts ptmp+rtmp, then Cp)
    const size_t OFF_SPAIR   = 76800000;    // 51,200,000 B
    const size_t OFF_RSTART  = 128000000;   // 150001 ints (600,016 B pad)
    const size_t OFF_SMALL   = 128600016;   // gbhist/gbstart/gbcur: 3*320 ints
    const size_t NEED        = 128603856;

    if (ws_size >= NEED) {
        float* X1      = (float*)(ws + OFF_X1);
        int2*  spair   = (int2*) (ws + OFF_SPAIR);
        int*   rstart  = (int*)  (ws + OFF_RSTART);
        int*   gbhist  = (int*)  (ws + OFF_SMALL);
        int*   gbstart = gbhist + 320;
        int*   gbcur   = gbhist + 640;

        // sort temporaries alias X1 (dead before GEMM partials / spmm use X1)
        int2* ptmp = (int2*)X1;                        // 51.2 MB
        int*  rtmp = (int*)((char*)X1 + 51200000);     // 25.6 MB
        float* Cp0 = X1;                               // GEMM partials (after sort)
        float* Cp2 = X1 + 2 * SZP;
        float* items = out + (size_t)N_USERS * 128;

        // ---- ego0: users interleaved into d_out ----
        build_user<<<(N_USERS * 16 + 255) / 256, 256, 0, stream>>>(
            (const float4*)image_pref, (const float4*)text_pref, (float4*)out);

        // ---- bucketed 2-pass row sort (also produces rstart) ----
        hipMemsetAsync(gbhist, 0, 320 * sizeof(int), stream);
        bucket_cnt<<<NCH, 256, 0, stream>>>(adj_rows, gbhist);
        scan_nbuck<<<1, 512, 0, stream>>>(gbhist, gbstart, gbcur);
        sort_pass1<<<NCH, 256, 0, stream>>>(adj_vals, adj_rows, adj_cols,
                                            gbcur, ptmp, rtmp);
        sort_pass2<<<NBUCK, 256, 0, stream>>>(ptmp, rtmp, gbstart, spair, rstart);
        set_tail<<<1, 64, 0, stream>>>(rstart);

        // ---- item GEMMs (partial sums into X1), fused add+bias+norm epilogues ----
        dim3 gimg((N_ITEMS + BM - 1) / BM, 2);
        gemm_tile<<<gimg, 256, 0, stream>>>(image_feats, W_img, Cp0, N_ITEMS, 4096, 2048);
        dim3 gtxt((N_ITEMS + BM - 1) / BM, 1);
        gemm_tile<<<gtxt, 256, 0, stream>>>(text_feats, W_txt, Cp2, N_ITEMS, 384, 384);
        epilogue_norm<<<(N_ITEMS + 3) / 4, 256, 0, stream>>>(Cp0, Cp0 + SZP, b_img,
                                                             items, N_ITEMS, 1);
        epilogue_norm<<<(N_ITEMS + 3) / 4, 256, 0, stream>>>(Cp2, Cp2, b_txt,
                                                             items + 64, N_ITEMS, 0);

        // ---- 2 propagation layers ----
        spmm_cols<<<NTOT / 2, 256, 0, stream>>>(spair, rstart, out, X1);
        spmm_cols<<<NTOT / 2, 256, 0, stream>>>(spair, rstart, X1, out);
        return;
    }

    // ================= fallback: round-1 atomic path =================
    float* wsf = (float*)d_ws;
    float* Ai = wsf;
    float* At = wsf + SZ;
    float* Bi = out;
    float* Bt = out + SZ;

    const int n4_pref = N_USERS * DD / 4;
    const int n4_ego  = (int)(SZ / 4);

    copy4<<<n4_pref / 256, 256, 0, stream>>>((const float4*)image_pref, (float4*)Ai, n4_pref);
    copy4<<<n4_pref / 256, 256, 0, stream>>>((const float4*)text_pref,  (float4*)At, n4_pref);

    gemm_bias<<<(N_ITEMS + 63) / 64, 256, 0, stream>>>(image_feats, W_img, b_img,
                                                       Ai + (size_t)N_USERS * DD, N_ITEMS, 4096, DD);
    gemm_bias<<<(N_ITEMS + 63) / 64, 256, 0, stream>>>(text_feats,  W_txt, b_txt,
                                                       At + (size_t)N_USERS * DD, N_ITEMS, 384, DD);
    l2norm_rows<<<(N_ITEMS + 3) / 4, 256, 0, stream>>>(Ai + (size_t)N_USERS * DD, N_ITEMS, DD);
    l2norm_rows<<<(N_ITEMS + 3) / 4, 256, 0, stream>>>(At + (size_t)N_USERS * DD, N_ITEMS, DD);

    const int spmm_blocks = (int)(((long long)NNZV * 16 + 255) / 256);

    scale4<<<(n4_ego + 255) / 256, 256, 0, stream>>>((const float4*)Ai, (float4*)Bi, n4_ego);
    spmm_atomic<<<spmm_blocks, 256, 0, stream>>>(adj_vals, adj_rows, adj_cols, Ai, Bi, NNZV);
    scale4<<<(n4_ego + 255) / 256, 256, 0, stream>>>((const float4*)At, (float4*)Bt, n4_ego);
    spmm_atomic<<<spmm_blocks, 256, 0, stream>>>(adj_vals, adj_rows, adj_cols, At, Bt, NNZV);

    scale4<<<(n4_ego + 255) / 256, 256, 0, stream>>>((const float4*)Bi, (float4*)Ai, n4_ego);
    spmm_atomic<<<spmm_blocks, 256, 0, stream>>>(adj_vals, adj_rows, adj_cols, Bi, Ai, NNZV);
    scale4<<<(n4_ego + 255) / 256, 256, 0, stream>>>((const float4*)Bt, (float4*)At, n4_ego);
    spmm_atomic<<<spmm_blocks, 256, 0, stream>>>(adj_vals, adj_rows, adj_cols, Bt, At, NNZV);

    finalize_k<<<(NTOT * 32) / 256, 256, 0, stream>>>((const float4*)Ai, (const float4*)At,
                                                      (float4*)out);
}

// Round 6
// 1332.393 us; speedup vs baseline: 4.1107x; 1.3260x over previous
//
#include <hip/hip_runtime.h>

#define N_USERS 100000
#define N_ITEMS 50000
#define NTOT    150000
#define DD      64
#define NNZV    6400000
#define ALPHA_  0.3f

#define BSHIFT  9
#define NBUCK   293        // ceil(150000 / 512)
#define CH      16384      // nnz chunk per pass-1 block
#define NCH     391        // ceil(NNZV / CH)

static constexpr size_t SZ  = (size_t)NTOT * DD;
static constexpr size_t SZP = (size_t)50048 * 64;   // padded GEMM partial buffer

typedef unsigned int  u32;
typedef unsigned short u16;

__device__ __forceinline__ u16 f2bf(float f) {       // fp32 -> bf16 RNE
    u32 u = __float_as_uint(f);
    u += 0x7fffu + ((u >> 16) & 1u);
    return (u16)(u >> 16);
}
__device__ __forceinline__ float bf_lo(u32 w) { return __uint_as_float(w << 16); }
__device__ __forceinline__ float bf_hi(u32 w) { return __uint_as_float(w & 0xffff0000u); }

// ================= LDS-staged fp32 GEMM tile: 128x64, microtile 8x4, BK=32 ======
#define BM 128
#define BK 32
__global__ __launch_bounds__(256) void gemm_tile(
    const float* __restrict__ A, const float* __restrict__ W,
    float* __restrict__ CpBase, int M, int K, int kchunk)
{
    __shared__ float As[BK][BM];
    __shared__ float Bs[BK][68];
    const int t  = threadIdx.x;
    const int tx = t & 15;
    const int ty = t >> 4;
    const int mblk = blockIdx.x * BM;
    const int k0beg = blockIdx.y * kchunk;
    const int k0end = k0beg + kchunk;
    float* Cp = CpBase + (size_t)blockIdx.y * SZP;

    const int arow  = t >> 1;
    const int akoff = (t & 1) * 16;
    const int wk = t >> 3;
    const int wn = (t & 7) * 8;

    float acc[8][4];
    #pragma unroll
    for (int r = 0; r < 8; ++r)
        #pragma unroll
        for (int c = 0; c < 4; ++c) acc[r][c] = 0.f;

    int gm = mblk + arow; if (gm >= M) gm = M - 1;
    const float* aprow = A + (size_t)gm * K;

    for (int k0 = k0beg; k0 < k0end; k0 += BK) {
        const float* ap = aprow + k0 + akoff;
        float4 a0 = *(const float4*)(ap + 0);
        float4 a1 = *(const float4*)(ap + 4);
        float4 a2 = *(const float4*)(ap + 8);
        float4 a3 = *(const float4*)(ap + 12);
        const float* wp = W + (size_t)(k0 + wk) * DD + wn;
        float4 w0 = *(const float4*)(wp + 0);
        float4 w1 = *(const float4*)(wp + 4);

        __syncthreads();
        As[akoff+ 0][arow] = a0.x; As[akoff+ 1][arow] = a0.y;
        As[akoff+ 2][arow] = a0.z; As[akoff+ 3][arow] = a0.w;
        As[akoff+ 4][arow] = a1.x; As[akoff+ 5][arow] = a1.y;
        As[akoff+ 6][arow] = a1.z; As[akoff+ 7][arow] = a1.w;
        As[akoff+ 8][arow] = a2.x; As[akoff+ 9][arow] = a2.y;
        As[akoff+10][arow] = a2.z; As[akoff+11][arow] = a2.w;
        As[akoff+12][arow] = a3.x; As[akoff+13][arow] = a3.y;
        As[akoff+14][arow] = a3.z; As[akoff+15][arow] = a3.w;
        *(float4*)&Bs[wk][wn + 0] = w0;
        *(float4*)&Bs[wk][wn + 4] = w1;
        __syncthreads();

        #pragma unroll
        for (int k = 0; k < BK; ++k) {
            const float4 af0 = *(const float4*)&As[k][ty * 8 + 0];
            const float4 af1 = *(const float4*)&As[k][ty * 8 + 4];
            const float4 wf  = *(const float4*)&Bs[k][tx * 4];
            acc[0][0] += af0.x*wf.x; acc[0][1] += af0.x*wf.y; acc[0][2] += af0.x*wf.z; acc[0][3] += af0.x*wf.w;
            acc[1][0] += af0.y*wf.x; acc[1][1] += af0.y*wf.y; acc[1][2] += af0.y*wf.z; acc[1][3] += af0.y*wf.w;
            acc[2][0] += af0.z*wf.x; acc[2][1] += af0.z*wf.y; acc[2][2] += af0.z*wf.z; acc[2][3] += af0.z*wf.w;
            acc[3][0] += af0.w*wf.x; acc[3][1] += af0.w*wf.y; acc[3][2] += af0.w*wf.z; acc[3][3] += af0.w*wf.w;
            acc[4][0] += af1.x*wf.x; acc[4][1] += af1.x*wf.y; acc[4][2] += af1.x*wf.z; acc[4][3] += af1.x*wf.w;
            acc[5][0] += af1.y*wf.x; acc[5][1] += af1.y*wf.y; acc[5][2] += af1.y*wf.z; acc[5][3] += af1.y*wf.w;
            acc[6][0] += af1.z*wf.x; acc[6][1] += af1.z*wf.y; acc[6][2] += af1.z*wf.z; acc[6][3] += af1.z*wf.w;
            acc[7][0] += af1.w*wf.x; acc[7][1] += af1.w*wf.y; acc[7][2] += af1.w*wf.z; acc[7][3] += af1.w*wf.w;
        }
    }

    #pragma unroll
    for (int r = 0; r < 8; ++r) {
        int m = mblk + ty * 8 + r;
        *(float4*)(Cp + (size_t)m * DD + tx * 4) =
            make_float4(acc[r][0], acc[r][1], acc[r][2], acc[r][3]);
    }
}

// ===== epilogue: v = Cp0+Cp1(opt)+bias; L2-norm; store fp32 (ld=128) + bf16 shadow =====
__global__ __launch_bounds__(256) void epilogue_norm(
    const float* __restrict__ Cp0, const float* __restrict__ Cp1,
    const float* __restrict__ bias, float* __restrict__ outp,
    u16* __restrict__ bfp, int nrows, int two)
{
    int row  = blockIdx.x * 4 + (threadIdx.x >> 6);
    int lane = threadIdx.x & 63;
    if (row >= nrows) return;
    float v = Cp0[(size_t)row * DD + lane] + bias[lane];
    if (two) v += Cp1[(size_t)row * DD + lane];
    float s = v * v;
    #pragma unroll
    for (int off = 32; off > 0; off >>= 1) s += __shfl_xor(s, off);
    v = v / fmaxf(sqrtf(s), 1e-12f);
    outp[(size_t)row * 128 + lane] = v;
    bfp [(size_t)row * 128 + lane] = f2bf(v);
}

// ====== interleave user prefs into X[row][0:64|64:128] (fp32) + bf16 shadow =====
__global__ __launch_bounds__(256) void build_user(const float4* __restrict__ ip,
                                                  const float4* __restrict__ tp,
                                                  float4* __restrict__ X,
                                                  ushort4* __restrict__ Xbf)
{
    int i = blockIdx.x * 256 + threadIdx.x;
    if (i >= N_USERS * 16) return;
    int row = i >> 4, q = i & 15;
    float4 vi = ip[i];
    float4 vt = tp[i];
    X[(size_t)row * 32 + q]      = vi;
    X[(size_t)row * 32 + 16 + q] = vt;
    ushort4 bi; bi.x = f2bf(vi.x); bi.y = f2bf(vi.y); bi.z = f2bf(vi.z); bi.w = f2bf(vi.w);
    ushort4 bt; bt.x = f2bf(vt.x); bt.y = f2bf(vt.y); bt.z = f2bf(vt.z); bt.w = f2bf(vt.w);
    Xbf[(size_t)row * 32 + q]      = bi;
    Xbf[(size_t)row * 32 + 16 + q] = bt;
}

// ================= bucketed 2-pass row sort =================================
__global__ __launch_bounds__(256) void bucket_cnt(const int* __restrict__ rows,
                                                  int* __restrict__ gbhist)
{
    __shared__ int cnt[NBUCK];
    int t = threadIdx.x;
    for (int i = t; i < NBUCK; i += 256) cnt[i] = 0;
    __syncthreads();
    int beg = blockIdx.x * CH;
    int end = beg + CH; if (end > NNZV) end = NNZV;
    for (int i = beg + t; i < end; i += 256)
        atomicAdd(&cnt[rows[i] >> BSHIFT], 1);
    __syncthreads();
    for (int i = t; i < NBUCK; i += 256)
        if (cnt[i]) atomicAdd(&gbhist[i], cnt[i]);
}

__global__ __launch_bounds__(512) void scan_nbuck(const int* __restrict__ gbhist,
                                                  int* __restrict__ gbstart,
                                                  int* __restrict__ gbcur)
{
    __shared__ int sh[512];
    int t = threadIdx.x;
    int v = (t < NBUCK) ? gbhist[t] : 0;
    sh[t] = v;
    __syncthreads();
    for (int off = 1; off < 512; off <<= 1) {
        int x = (t >= off) ? sh[t - off] : 0;
        __syncthreads();
        sh[t] += x;
        __syncthreads();
    }
    if (t < NBUCK) {
        int e = sh[t] - v;
        gbstart[t] = e;
        gbcur[t]   = e;
    }
}

__global__ __launch_bounds__(256) void sort_pass1(
    const float* __restrict__ vals, const int* __restrict__ rows,
    const int* __restrict__ cols, int* __restrict__ gbcur,
    int2* __restrict__ ptmp, int* __restrict__ rtmp)
{
    __shared__ int cnt[NBUCK];
    __shared__ int base[NBUCK];
    int t = threadIdx.x;
    int beg = blockIdx.x * CH;
    int end = beg + CH; if (end > NNZV) end = NNZV;

    for (int i = t; i < NBUCK; i += 256) cnt[i] = 0;
    __syncthreads();
    for (int i = beg + t; i < end; i += 256)
        atomicAdd(&cnt[rows[i] >> BSHIFT], 1);
    __syncthreads();
    for (int i = t; i < NBUCK; i += 256) {
        int c = cnt[i];
        base[i] = c ? atomicAdd(&gbcur[i], c) : 0;
    }
    __syncthreads();
    for (int i = t; i < NBUCK; i += 256) cnt[i] = 0;
    __syncthreads();
    for (int i = beg + t; i < end; i += 256) {
        int r = rows[i];
        int b = r >> BSHIFT;
        int rank = atomicAdd(&cnt[b], 1);
        int p = base[b] + rank;
        ptmp[p] = make_int2(__float_as_int(vals[i]), cols[i]);
        rtmp[p] = r;
    }
}

__global__ __launch_bounds__(256) void sort_pass2(
    const int2* __restrict__ ptmp, const int* __restrict__ rtmp,
    const int* __restrict__ gbstart, int2* __restrict__ spair,
    int* __restrict__ rstart)
{
    __shared__ int rcnt[512];
    __shared__ int cur[512];
    __shared__ int s2[256];
    const int b = blockIdx.x;
    const int t = threadIdx.x;
    const int rbase  = b << BSHIFT;
    const int bstart = gbstart[b];
    const int bend   = (b == NBUCK - 1) ? NNZV : gbstart[b + 1];

    rcnt[t] = 0; rcnt[t + 256] = 0;
    __syncthreads();
    for (int i = bstart + t; i < bend; i += 256)
        atomicAdd(&rcnt[rtmp[i] - rbase], 1);
    __syncthreads();

    int a0 = rcnt[2 * t], a1 = rcnt[2 * t + 1];
    s2[t] = a0 + a1;
    __syncthreads();
    for (int off = 1; off < 256; off <<= 1) {
        int x = (t >= off) ? s2[t - off] : 0;
        __syncthreads();
        s2[t] += x;
        __syncthreads();
    }
    int epair = s2[t] - (a0 + a1);
    int c0 = bstart + epair;
    int c1 = c0 + a0;
    cur[2 * t]     = c0;
    cur[2 * t + 1] = c1;
    int r0 = rbase + 2 * t;
    if (r0 < NTOT)     rstart[r0]     = c0;
    if (r0 + 1 < NTOT) rstart[r0 + 1] = c1;
    __syncthreads();

    for (int i = bstart + t; i < bend; i += 256) {
        int r = rtmp[i];
        int p = atomicAdd(&cur[r - rbase], 1);
        spair[p] = ptmp[i];
    }
}

__global__ void set_tail(int* __restrict__ rstart)
{
    if (threadIdx.x == 0 && blockIdx.x == 0) rstart[NTOT] = NNZV;
}

// ====== per-row SpMM, 1 wave/row, bf16 gathers (uint = 2 cols), fp32 alpha+out ======
// Xout[row][2t,2t+1] = sum_j v_j * Xbf[col_j][2t,2t+1] + ALPHA * Xin[row][2t,2t+1]
__global__ __launch_bounds__(256) void spmm_wave(
    const int2* __restrict__ spair, const int* __restrict__ rstart,
    const u32* __restrict__ Xbf, const float* __restrict__ Xin,
    float* __restrict__ Xout, u32* __restrict__ XbfOut)
{
    int row = blockIdx.x * 4 + (threadIdx.x >> 6);
    int t   = threadIdx.x & 63;
    int beg = rstart[row];
    int end = rstart[row + 1];
    float a0 = 0.f, a1 = 0.f, b0 = 0.f, b1 = 0.f;
    int j = beg;
    for (; j + 8 <= end; j += 8) {
        int2 p0 = spair[j];     int2 p1 = spair[j + 1];
        int2 p2 = spair[j + 2]; int2 p3 = spair[j + 3];
        int2 p4 = spair[j + 4]; int2 p5 = spair[j + 5];
        int2 p6 = spair[j + 6]; int2 p7 = spair[j + 7];
        u32 w0 = Xbf[(size_t)p0.y * 64 + t];
        u32 w1 = Xbf[(size_t)p1.y * 64 + t];
        u32 w2 = Xbf[(size_t)p2.y * 64 + t];
        u32 w3 = Xbf[(size_t)p3.y * 64 + t];
        u32 w4 = Xbf[(size_t)p4.y * 64 + t];
        u32 w5 = Xbf[(size_t)p5.y * 64 + t];
        u32 w6 = Xbf[(size_t)p6.y * 64 + t];
        u32 w7 = Xbf[(size_t)p7.y * 64 + t];
        float v0 = __int_as_float(p0.x), v1 = __int_as_float(p1.x);
        float v2 = __int_as_float(p2.x), v3 = __int_as_float(p3.x);
        float v4 = __int_as_float(p4.x), v5 = __int_as_float(p5.x);
        float v6 = __int_as_float(p6.x), v7 = __int_as_float(p7.x);
        a0 += v0 * bf_lo(w0); a1 += v0 * bf_hi(w0);
        b0 += v1 * bf_lo(w1); b1 += v1 * bf_hi(w1);
        a0 += v2 * bf_lo(w2); a1 += v2 * bf_hi(w2);
        b0 += v3 * bf_lo(w3); b1 += v3 * bf_hi(w3);
        a0 += v4 * bf_lo(w4); a1 += v4 * bf_hi(w4);
        b0 += v5 * bf_lo(w5); b1 += v5 * bf_hi(w5);
        a0 += v6 * bf_lo(w6); a1 += v6 * bf_hi(w6);
        b0 += v7 * bf_lo(w7); b1 += v7 * bf_hi(w7);
    }
    for (; j < end; ++j) {
        int2 p = spair[j];
        u32 w = Xbf[(size_t)p.y * 64 + t];
        float v = __int_as_float(p.x);
        a0 += v * bf_lo(w); a1 += v * bf_hi(w);
    }
    float2 xr = *(const float2*)(Xin + (size_t)row * 128 + 2 * t);
    float o0 = a0 + b0 + ALPHA_ * xr.x;
    float o1 = a1 + b1 + ALPHA_ * xr.y;
    *(float2*)(Xout + (size_t)row * 128 + 2 * t) = make_float2(o0, o1);
    if (XbfOut)
        XbfOut[(size_t)row * 64 + t] = (u32)f2bf(o0) | ((u32)f2bf(o1) << 16);
}

// ================= fallback (round-1) kernels ===============================
__global__ __launch_bounds__(256) void copy4(const float4* __restrict__ src,
                                             float4* __restrict__ dst, int n4)
{
    int i = blockIdx.x * 256 + threadIdx.x;
    if (i < n4) dst[i] = src[i];
}

__global__ __launch_bounds__(256) void gemm_bias(
    const float* __restrict__ A, const float* __restrict__ W,
    const float* __restrict__ bias, float* __restrict__ C, int M, int K, int ldc)
{
    __shared__ float As2[16][64];
    __shared__ float Bs2[16][64];
    const int t  = threadIdx.x;
    const int tx = t & 15, ty = t >> 4;
    const int lr = t >> 2;
    const int lk = (t & 3) << 2;
    const int brow = t >> 4;
    const int bc   = (t & 15) << 2;
    const int block_row = blockIdx.x << 6;

    float acc[4][4] = {{0.f,0.f,0.f,0.f},{0.f,0.f,0.f,0.f},{0.f,0.f,0.f,0.f},{0.f,0.f,0.f,0.f}};
    const int grow = block_row + lr;
    const bool arow_ok = (grow < M);
    const float* Aptr = A + (size_t)grow * K;

    for (int k0 = 0; k0 < K; k0 += 16) {
        float4 av = make_float4(0.f, 0.f, 0.f, 0.f);
        if (arow_ok) av = *(const float4*)(Aptr + k0 + lk);
        As2[lk+0][lr] = av.x; As2[lk+1][lr] = av.y; As2[lk+2][lr] = av.z; As2[lk+3][lr] = av.w;
        *(float4*)&Bs2[brow][bc] = *(const float4*)(W + (size_t)(k0 + brow) * DD + bc);
        __syncthreads();
        #pragma unroll
        for (int k = 0; k < 16; ++k) {
            float4 a = *(const float4*)&As2[k][ty << 2];
            float4 b = *(const float4*)&Bs2[k][tx << 2];
            acc[0][0] += a.x*b.x; acc[0][1] += a.x*b.y; acc[0][2] += a.x*b.z; acc[0][3] += a.x*b.w;
            acc[1][0] += a.y*b.x; acc[1][1] += a.y*b.y; acc[1][2] += a.y*b.z; acc[1][3] += a.y*b.w;
            acc[2][0] += a.z*b.x; acc[2][1] += a.z*b.y; acc[2][2] += a.z*b.z; acc[2][3] += a.z*b.w;
            acc[3][0] += a.w*b.x; acc[3][1] += a.w*b.y; acc[3][2] += a.w*b.z; acc[3][3] += a.w*b.w;
        }
        __syncthreads();
    }
    const float4 bv = *(const float4*)(bias + (tx << 2));
    #pragma unroll
    for (int i = 0; i < 4; ++i) {
        int row = block_row + (ty << 2) + i;
        if (row < M) {
            float4 o = make_float4(acc[i][0] + bv.x, acc[i][1] + bv.y,
                                   acc[i][2] + bv.z, acc[i][3] + bv.w);
            *(float4*)(C + (size_t)row * ldc + (tx << 2)) = o;
        }
    }
}

__global__ __launch_bounds__(256) void l2norm_rows(float* __restrict__ x, int nrows, int ld)
{
    int row  = blockIdx.x * 4 + (threadIdx.x >> 6);
    int lane = threadIdx.x & 63;
    if (row >= nrows) return;
    float v = x[(size_t)row * ld + lane];
    float s = v * v;
    #pragma unroll
    for (int off = 32; off > 0; off >>= 1) s += __shfl_xor(s, off);
    float n = sqrtf(s);
    x[(size_t)row * ld + lane] = v / fmaxf(n, 1e-12f);
}

__global__ __launch_bounds__(256) void scale4(const float4* __restrict__ src,
                                              float4* __restrict__ dst, int n4)
{
    int i = blockIdx.x * 256 + threadIdx.x;
    if (i < n4) {
        float4 v = src[i];
        dst[i] = make_float4(ALPHA_*v.x, ALPHA_*v.y, ALPHA_*v.z, ALPHA_*v.w);
    }
}

__global__ __launch_bounds__(256) void spmm_atomic(
    const float* __restrict__ vals, const int* __restrict__ rows,
    const int* __restrict__ cols, const float* __restrict__ x,
    float* __restrict__ out, int nnz)
{
    long long tid = (long long)blockIdx.x * 256 + threadIdx.x;
    int g = (int)(tid >> 4);
    if (g >= nnz) return;
    int lane = (int)(tid & 15);
    float v = vals[g];
    int r = rows[g], c = cols[g];
    float4 xv = *((const float4*)(x + (size_t)c * DD) + lane);
    float* o = out + (size_t)r * DD + (lane << 2);
    atomicAdd(o + 0, v * xv.x);
    atomicAdd(o + 1, v * xv.y);
    atomicAdd(o + 2, v * xv.z);
    atomicAdd(o + 3, v * xv.w);
}

__global__ __launch_bounds__(256) void finalize_k(
    const float4* __restrict__ egoI, const float4* __restrict__ egoT,
    float4* __restrict__ out)
{
    int tid = blockIdx.x * 256 + threadIdx.x;
    int row = tid >> 5, q = tid & 31;
    if (row >= NTOT) return;
    float4 v = (q < 16) ? egoI[(size_t)row * 16 + q] : egoT[(size_t)row * 16 + (q - 16)];
    out[tid] = v;
}

// ============================================================================
extern "C" void kernel_launch(void* const* d_in, const int* in_sizes, int n_in,
                              void* d_out, int out_size, void* d_ws, size_t ws_size,
                              hipStream_t stream)
{
    const float* image_feats = (const float*)d_in[0];
    const float* text_feats  = (const float*)d_in[1];
    const float* image_pref  = (const float*)d_in[2];
    const float* text_pref   = (const float*)d_in[3];
    const float* W_img       = (const float*)d_in[4];
    const float* b_img       = (const float*)d_in[5];
    const float* W_txt       = (const float*)d_in[6];
    const float* b_txt       = (const float*)d_in[7];
    const float* adj_vals    = (const float*)d_in[8];
    const int*   adj_rows    = (const int*)d_in[9];
    const int*   adj_cols    = (const int*)d_in[10];

    float* out = (float*)d_out;
    char*  ws  = (char*)d_ws;

    const size_t OFF_X1      = 0;           // 76,800,000 B (X1; aliases ptmp+rtmp, then Cp)
    const size_t OFF_SPAIR   = 76800000;    // 51,200,000 B
    const size_t OFF_RSTART  = 128000000;   // 150001 ints (600,016 B pad)
    const size_t OFF_SMALL   = 128600016;   // gbhist/gbstart/gbcur (pad to 4144)
    const size_t OFF_XB0     = 128604160;   // 38,400,000 B bf16 shadow of X0
    const size_t OFF_XB1     = 167004160;   // 38,400,000 B bf16 shadow of X1
    const size_t NEED        = 205404160;

    if (ws_size >= NEED) {
        float* X1      = (float*)(ws + OFF_X1);
        int2*  spair   = (int2*) (ws + OFF_SPAIR);
        int*   rstart  = (int*)  (ws + OFF_RSTART);
        int*   gbhist  = (int*)  (ws + OFF_SMALL);
        int*   gbstart = gbhist + 320;
        int*   gbcur   = gbhist + 640;
        u32*   Xb0     = (u32*)  (ws + OFF_XB0);
        u32*   Xb1     = (u32*)  (ws + OFF_XB1);

        // sort temporaries alias X1 (dead before GEMM partials / spmm use X1)
        int2* ptmp = (int2*)X1;                        // 51.2 MB
        int*  rtmp = (int*)((char*)X1 + 51200000);     // 25.6 MB
        float* Cp0 = X1;                               // GEMM partials (after sort)
        float* Cp2 = X1 + 2 * SZP;
        float* items = out + (size_t)N_USERS * 128;
        u16*   items_bf = (u16*)Xb0 + (size_t)N_USERS * 128;

        // ---- ego0: users interleaved into d_out + bf16 shadow ----
        build_user<<<(N_USERS * 16 + 255) / 256, 256, 0, stream>>>(
            (const float4*)image_pref, (const float4*)text_pref,
            (float4*)out, (ushort4*)Xb0);

        // ---- bucketed 2-pass row sort (also produces rstart) ----
        hipMemsetAsync(gbhist, 0, 320 * sizeof(int), stream);
        bucket_cnt<<<NCH, 256, 0, stream>>>(adj_rows, gbhist);
        scan_nbuck<<<1, 512, 0, stream>>>(gbhist, gbstart, gbcur);
        sort_pass1<<<NCH, 256, 0, stream>>>(adj_vals, adj_rows, adj_cols,
                                            gbcur, ptmp, rtmp);
        sort_pass2<<<NBUCK, 256, 0, stream>>>(ptmp, rtmp, gbstart, spair, rstart);
        set_tail<<<1, 64, 0, stream>>>(rstart);

        // ---- item GEMMs (partials into X1), fused add+bias+norm+bf16 epilogues ----
        dim3 gimg((N_ITEMS + BM - 1) / BM, 2);
        gemm_tile<<<gimg, 256, 0, stream>>>(image_feats, W_img, Cp0, N_ITEMS, 4096, 2048);
        dim3 gtxt((N_ITEMS + BM - 1) / BM, 1);
        gemm_tile<<<gtxt, 256, 0, stream>>>(text_feats, W_txt, Cp2, N_ITEMS, 384, 384);
        epilogue_norm<<<(N_ITEMS + 3) / 4, 256, 0, stream>>>(Cp0, Cp0 + SZP, b_img,
                                                             items, items_bf, N_ITEMS, 1);
        epilogue_norm<<<(N_ITEMS + 3) / 4, 256, 0, stream>>>(Cp2, Cp2, b_txt,
                                                             items + 64, items_bf + 64,
                                                             N_ITEMS, 0);

        // ---- 2 propagation layers (bf16 gathers, fp32 alpha+output) ----
        spmm_wave<<<NTOT / 4, 256, 0, stream>>>(spair, rstart, Xb0, out, X1, Xb1);
        spmm_wave<<<NTOT / 4, 256, 0, stream>>>(spair, rstart, Xb1, X1, out, (u32*)nullptr);
        return;
    }

    // ================= fallback: round-1 atomic path =================
    float* wsf = (float*)d_ws;
    float* Ai = wsf;
    float* At = wsf + SZ;
    float* Bi = out;
    float* Bt = out + SZ;

    const int n4_pref = N_USERS * DD / 4;
    const int n4_ego  = (int)(SZ / 4);

    copy4<<<n4_pref / 256, 256, 0, stream>>>((const float4*)image_pref, (float4*)Ai, n4_pref);
    copy4<<<n4_pref / 256, 256, 0, stream>>>((const float4*)text_pref,  (float4*)At, n4_pref);

    gemm_bias<<<(N_ITEMS + 63) / 64, 256, 0, stream>>>(image_feats, W_img, b_img,
                                                       Ai + (size_t)N_USERS * DD, N_ITEMS, 4096, DD);
    gemm_bias<<<(N_ITEMS + 63) / 64, 256, 0, stream>>>(text_feats,  W_txt, b_txt,
                                                       At + (size_t)N_USERS * DD, N_ITEMS, 384, DD);
    l2norm_rows<<<(N_ITEMS + 3) / 4, 256, 0, stream>>>(Ai + (size_t)N_USERS * DD, N_ITEMS, DD);
    l2norm_rows<<<(N_ITEMS + 3) / 4, 256, 0, stream>>>(At + (size_t)N_USERS * DD, N_ITEMS, DD);

    const int spmm_blocks = (int)(((long long)NNZV * 16 + 255) / 256);

    scale4<<<(n4_ego + 255) / 256, 256, 0, stream>>>((const float4*)Ai, (float4*)Bi, n4_ego);
    spmm_atomic<<<spmm_blocks, 256, 0, stream>>>(adj_vals, adj_rows, adj_cols, Ai, Bi, NNZV);
    scale4<<<(n4_ego + 255) / 256, 256, 0, stream>>>((const float4*)At, (float4*)Bt, n4_ego);
    spmm_atomic<<<spmm_blocks, 256, 0, stream>>>(adj_vals, adj_rows, adj_cols, At, Bt, NNZV);

    scale4<<<(n4_ego + 255) / 256, 256, 0, stream>>>((const float4*)Bi, (float4*)Ai, n4_ego);
    spmm_atomic<<<spmm_blocks, 256, 0, stream>>>(adj_vals, adj_rows, adj_cols, Bi, Ai, NNZV);
    scale4<<<(n4_ego + 255) / 256, 256, 0, stream>>>((const float4*)Bt, (float4*)At, n4_ego);
    spmm_atomic<<<spmm_blocks, 256, 0, stream>>>(adj_vals, adj_rows, adj_cols, Bt, At, NNZV);

    finalize_k<<<(NTOT * 32) / 256, 256, 0, stream>>>((const float4*)Ai, (const float4*)At,
                                                      (float4*)out);
}

// Round 7
// 1003.090 us; speedup vs baseline: 5.4602x; 1.3283x over previous
//
#include <hip/hip_runtime.h>

#define N_USERS 100000
#define N_ITEMS 50000
#define NTOT    150000
#define DD      64
#define NNZV    6400000
#define ALPHA_  0.3f

#define BSHIFT  9
#define NBUCK   293        // ceil(150000 / 512)
#define CH      16384      // nnz chunk per pass-1 block
#define NCH     391        // ceil(NNZV / CH)

static constexpr size_t SZ = (size_t)NTOT * DD;

typedef unsigned int   u32;
typedef unsigned short u16;
typedef __attribute__((ext_vector_type(8))) short bf16x8;
typedef __attribute__((ext_vector_type(4))) float f32x4;

__device__ __forceinline__ u16 f2bf(float f) {       // fp32 -> bf16 RNE
    u32 u = __float_as_uint(f);
    u += 0x7fffu + ((u >> 16) & 1u);
    return (u16)(u >> 16);
}
__device__ __forceinline__ float bf_lo(u32 w) { return __uint_as_float(w << 16); }
__device__ __forceinline__ float bf_hi(u32 w) { return __uint_as_float(w & 0xffff0000u); }

// ===== W fp32 [K][64] -> fragment-ordered bf16: dword idx = ks*1024 + nt*256 + l*4 + d =====
// fragment (ks,nt,lane l): 8 bf16 = W[ks*32 + (l>>4)*8 + j][nt*16 + (l&15)], j ascending
__global__ __launch_bounds__(256) void convert_wf(const float* __restrict__ W,
                                                  u32* __restrict__ Wf, int K)
{
    int tid = blockIdx.x * 256 + threadIdx.x;
    int total = (K >> 5) * 1024;
    if (tid >= total) return;
    int d  = tid & 3;
    int l  = (tid >> 2) & 63;
    int nt = (tid >> 8) & 3;
    int ks = tid >> 10;
    int k   = (ks << 5) + ((l >> 4) << 3) + (d << 1);
    int col = (nt << 4) + (l & 15);
    u16 lo = f2bf(W[(size_t)k * DD + col]);
    u16 hi = f2bf(W[(size_t)(k + 1) * DD + col]);
    Wf[tid] = (u32)lo | ((u32)hi << 16);
}

// ===== MFMA GEMM, fused bias + L2-norm, bf16 output at ld=128 ===============
// 256 thr = 4 waves; wave w owns rows [blk*64 + w*16, +16), all 64 cols.
// A fragments loaded straight from global fp32 (no LDS), cvt to bf16 in-reg.
__global__ __launch_bounds__(256) void gemm_mfma(
    const float* __restrict__ A, const int4* __restrict__ Wf4,
    const float* __restrict__ bias, u16* __restrict__ bfp, int M, int K)
{
    const int w  = threadIdx.x >> 6;
    const int l  = threadIdx.x & 63;
    const int lr = l & 15;
    const int lk = l >> 4;
    const int rbase = blockIdx.x * 64 + w * 16;

    f32x4 acc0 = {0.f,0.f,0.f,0.f}, acc1 = acc0, acc2 = acc0, acc3 = acc0;

    int gr = rbase + lr; if (gr >= M) gr = M - 1;
    const float* ap = A + (size_t)gr * K + lk * 8;

    for (int ks = 0; ks < K; ks += 32) {
        float4 a0 = *(const float4*)(ap + ks);
        float4 a1 = *(const float4*)(ap + ks + 4);
        int4 av;
        av.x = (int)((u32)f2bf(a0.x) | ((u32)f2bf(a0.y) << 16));
        av.y = (int)((u32)f2bf(a0.z) | ((u32)f2bf(a0.w) << 16));
        av.z = (int)((u32)f2bf(a1.x) | ((u32)f2bf(a1.y) << 16));
        av.w = (int)((u32)f2bf(a1.z) | ((u32)f2bf(a1.w) << 16));
        bf16x8 af = *(bf16x8*)&av;
        const int4* wp = Wf4 + (size_t)(ks >> 5) * 256 + l;
        int4 w0 = wp[0], w1 = wp[64], w2 = wp[128], w3 = wp[192];
        acc0 = __builtin_amdgcn_mfma_f32_16x16x32_bf16(af, *(bf16x8*)&w0, acc0, 0, 0, 0);
        acc1 = __builtin_amdgcn_mfma_f32_16x16x32_bf16(af, *(bf16x8*)&w1, acc1, 0, 0, 0);
        acc2 = __builtin_amdgcn_mfma_f32_16x16x32_bf16(af, *(bf16x8*)&w2, acc2, 0, 0, 0);
        acc3 = __builtin_amdgcn_mfma_f32_16x16x32_bf16(af, *(bf16x8*)&w3, acc3, 0, 0, 0);
    }

    // D layout: col = nt*16 + (l&15), row = rbase + (l>>4)*4 + reg
    float bv0 = bias[lr], bv1 = bias[16 + lr], bv2 = bias[32 + lr], bv3 = bias[48 + lr];
    #pragma unroll
    for (int r = 0; r < 4; ++r) {
        float v0 = acc0[r] + bv0;
        float v1 = acc1[r] + bv1;
        float v2 = acc2[r] + bv2;
        float v3 = acc3[r] + bv3;
        float s = v0*v0 + v1*v1 + v2*v2 + v3*v3;
        s += __shfl_xor(s, 1); s += __shfl_xor(s, 2);
        s += __shfl_xor(s, 4); s += __shfl_xor(s, 8);
        float inv = 1.f / fmaxf(sqrtf(s), 1e-12f);
        int row = rbase + lk * 4 + r;
        if (row < M) {
            u16* bp = bfp + (size_t)row * 128;
            bp[lr]      = f2bf(v0 * inv);
            bp[16 + lr] = f2bf(v1 * inv);
            bp[32 + lr] = f2bf(v2 * inv);
            bp[48 + lr] = f2bf(v3 * inv);
        }
    }
}

// ====== interleave user prefs into bf16 shadow X[row][0:64|64:128] ==========
__global__ __launch_bounds__(256) void build_user(const float4* __restrict__ ip,
                                                  const float4* __restrict__ tp,
                                                  ushort4* __restrict__ Xbf)
{
    int i = blockIdx.x * 256 + threadIdx.x;
    if (i >= N_USERS * 16) return;
    int row = i >> 4, q = i & 15;
    float4 vi = ip[i];
    float4 vt = tp[i];
    ushort4 bi; bi.x = f2bf(vi.x); bi.y = f2bf(vi.y); bi.z = f2bf(vi.z); bi.w = f2bf(vi.w);
    ushort4 bt; bt.x = f2bf(vt.x); bt.y = f2bf(vt.y); bt.z = f2bf(vt.z); bt.w = f2bf(vt.w);
    Xbf[(size_t)row * 32 + q]      = bi;
    Xbf[(size_t)row * 32 + 16 + q] = bt;
}

// ================= bucketed 2-pass row sort (packed row-local in col bits) ==
__global__ __launch_bounds__(256) void bucket_cnt(const int* __restrict__ rows,
                                                  int* __restrict__ gbhist)
{
    __shared__ int cnt[NBUCK];
    int t = threadIdx.x;
    for (int i = t; i < NBUCK; i += 256) cnt[i] = 0;
    __syncthreads();
    int beg = blockIdx.x * CH;
    int end = beg + CH; if (end > NNZV) end = NNZV;
    for (int i = beg + t; i < end; i += 256)
        atomicAdd(&cnt[rows[i] >> BSHIFT], 1);
    __syncthreads();
    for (int i = t; i < NBUCK; i += 256)
        if (cnt[i]) atomicAdd(&gbhist[i], cnt[i]);
}

__global__ __launch_bounds__(512) void scan_nbuck(const int* __restrict__ gbhist,
                                                  int* __restrict__ gbstart,
                                                  int* __restrict__ gbcur)
{
    __shared__ int sh[512];
    int t = threadIdx.x;
    int v = (t < NBUCK) ? gbhist[t] : 0;
    sh[t] = v;
    __syncthreads();
    for (int off = 1; off < 512; off <<= 1) {
        int x = (t >= off) ? sh[t - off] : 0;
        __syncthreads();
        sh[t] += x;
        __syncthreads();
    }
    if (t < NBUCK) {
        int e = sh[t] - v;
        gbstart[t] = e;
        gbcur[t]   = e;
    }
}

// pass 1: bin into bucket-grouped ptmp; row-local (9b) packed into col bits 18..26
__global__ __launch_bounds__(256) void sort_pass1(
    const float* __restrict__ vals, const int* __restrict__ rows,
    const int* __restrict__ cols, int* __restrict__ gbcur,
    int2* __restrict__ ptmp)
{
    __shared__ int cnt[NBUCK];
    __shared__ int base[NBUCK];
    int t = threadIdx.x;
    int beg = blockIdx.x * CH;
    int end = beg + CH; if (end > NNZV) end = NNZV;

    for (int i = t; i < NBUCK; i += 256) cnt[i] = 0;
    __syncthreads();
    for (int i = beg + t; i < end; i += 256)
        atomicAdd(&cnt[rows[i] >> BSHIFT], 1);
    __syncthreads();
    for (int i = t; i < NBUCK; i += 256) {
        int c = cnt[i];
        base[i] = c ? atomicAdd(&gbcur[i], c) : 0;
    }
    __syncthreads();
    for (int i = t; i < NBUCK; i += 256) cnt[i] = 0;
    __syncthreads();
    for (int i = beg + t; i < end; i += 256) {
        int r = rows[i];
        int b = r >> BSHIFT;
        int rank = atomicAdd(&cnt[b], 1);
        int p = base[b] + rank;
        ptmp[p] = make_int2(__float_as_int(vals[i]), cols[i] | ((r & 511) << 18));
    }
}

// pass 2: one block per bucket; LDS row hist + scan (emits rstart); in-region scatter
__global__ __launch_bounds__(256) void sort_pass2(
    const int2* __restrict__ ptmp, const int* __restrict__ gbstart,
    int2* __restrict__ spair, int* __restrict__ rstart)
{
    __shared__ int rcnt[512];
    __shared__ int cur[512];
    __shared__ int s2[256];
    const int b = blockIdx.x;
    const int t = threadIdx.x;
    const int bstart = gbstart[b];
    const int bend   = (b == NBUCK - 1) ? NNZV : gbstart[b + 1];

    rcnt[t] = 0; rcnt[t + 256] = 0;
    __syncthreads();
    for (int i = bstart + t; i < bend; i += 256)
        atomicAdd(&rcnt[(ptmp[i].y >> 18) & 511], 1);
    __syncthreads();

    int a0 = rcnt[2 * t], a1 = rcnt[2 * t + 1];
    s2[t] = a0 + a1;
    __syncthreads();
    for (int off = 1; off < 256; off <<= 1) {
        int x = (t >= off) ? s2[t - off] : 0;
        __syncthreads();
        s2[t] += x;
        __syncthreads();
    }
    int epair = s2[t] - (a0 + a1);
    int c0 = bstart + epair;
    int c1 = c0 + a0;
    cur[2 * t]     = c0;
    cur[2 * t + 1] = c1;
    int r0 = (b << BSHIFT) + 2 * t;
    if (r0 < NTOT)     rstart[r0]     = c0;
    if (r0 + 1 < NTOT) rstart[r0 + 1] = c1;
    __syncthreads();

    for (int i = bstart + t; i < bend; i += 256) {
        int2 v = ptmp[i];
        int p = atomicAdd(&cur[(v.y >> 18) & 511], 1);
        spair[p] = make_int2(v.x, v.y & 0x3FFFF);
    }
}

__global__ void set_tail(int* __restrict__ rstart)
{
    if (threadIdx.x == 0 && blockIdx.x == 0) rstart[NTOT] = NNZV;
}

// ====== per-row SpMM, 1 wave/row, bf16 gathers + bf16 alpha, fp32 accum =====
__global__ __launch_bounds__(256) void spmm_wave(
    const int2* __restrict__ spair, const int* __restrict__ rstart,
    const u32* __restrict__ Xbf, float* __restrict__ Xout,
    u32* __restrict__ XbfOut)
{
    int row = blockIdx.x * 4 + (threadIdx.x >> 6);
    int t   = threadIdx.x & 63;
    int beg = rstart[row];
    int end = rstart[row + 1];
    float a0 = 0.f, a1 = 0.f, b0 = 0.f, b1 = 0.f;
    int j = beg;
    for (; j + 8 <= end; j += 8) {
        int2 p0 = spair[j];     int2 p1 = spair[j + 1];
        int2 p2 = spair[j + 2]; int2 p3 = spair[j + 3];
        int2 p4 = spair[j + 4]; int2 p5 = spair[j + 5];
        int2 p6 = spair[j + 6]; int2 p7 = spair[j + 7];
        u32 w0 = Xbf[(size_t)p0.y * 64 + t];
        u32 w1 = Xbf[(size_t)p1.y * 64 + t];
        u32 w2 = Xbf[(size_t)p2.y * 64 + t];
        u32 w3 = Xbf[(size_t)p3.y * 64 + t];
        u32 w4 = Xbf[(size_t)p4.y * 64 + t];
        u32 w5 = Xbf[(size_t)p5.y * 64 + t];
        u32 w6 = Xbf[(size_t)p6.y * 64 + t];
        u32 w7 = Xbf[(size_t)p7.y * 64 + t];
        float v0 = __int_as_float(p0.x), v1 = __int_as_float(p1.x);
        float v2 = __int_as_float(p2.x), v3 = __int_as_float(p3.x);
        float v4 = __int_as_float(p4.x), v5 = __int_as_float(p5.x);
        float v6 = __int_as_float(p6.x), v7 = __int_as_float(p7.x);
        a0 += v0 * bf_lo(w0); a1 += v0 * bf_hi(w0);
        b0 += v1 * bf_lo(w1); b1 += v1 * bf_hi(w1);
        a0 += v2 * bf_lo(w2); a1 += v2 * bf_hi(w2);
        b0 += v3 * bf_lo(w3); b1 += v3 * bf_hi(w3);
        a0 += v4 * bf_lo(w4); a1 += v4 * bf_hi(w4);
        b0 += v5 * bf_lo(w5); b1 += v5 * bf_hi(w5);
        a0 += v6 * bf_lo(w6); a1 += v6 * bf_hi(w6);
        b0 += v7 * bf_lo(w7); b1 += v7 * bf_hi(w7);
    }
    for (; j < end; ++j) {
        int2 p = spair[j];
        u32 w = Xbf[(size_t)p.y * 64 + t];
        float v = __int_as_float(p.x);
        a0 += v * bf_lo(w); a1 += v * bf_hi(w);
    }
    u32 xr = Xbf[(size_t)row * 64 + t];
    float o0 = a0 + b0 + ALPHA_ * bf_lo(xr);
    float o1 = a1 + b1 + ALPHA_ * bf_hi(xr);
    if (Xout)
        *(float2*)(Xout + (size_t)row * 128 + 2 * t) = make_float2(o0, o1);
    if (XbfOut)
        XbfOut[(size_t)row * 64 + t] = (u32)f2bf(o0) | ((u32)f2bf(o1) << 16);
}

// ================= fallback (round-1) kernels ===============================
__global__ __launch_bounds__(256) void copy4(const float4* __restrict__ src,
                                             float4* __restrict__ dst, int n4)
{
    int i = blockIdx.x * 256 + threadIdx.x;
    if (i < n4) dst[i] = src[i];
}

__global__ __launch_bounds__(256) void gemm_bias(
    const float* __restrict__ A, const float* __restrict__ W,
    const float* __restrict__ bias, float* __restrict__ C, int M, int K, int ldc)
{
    __shared__ float As2[16][64];
    __shared__ float Bs2[16][64];
    const int t  = threadIdx.x;
    const int tx = t & 15, ty = t >> 4;
    const int lr = t >> 2;
    const int lk = (t & 3) << 2;
    const int brow = t >> 4;
    const int bc   = (t & 15) << 2;
    const int block_row = blockIdx.x << 6;

    float acc[4][4] = {{0.f,0.f,0.f,0.f},{0.f,0.f,0.f,0.f},{0.f,0.f,0.f,0.f},{0.f,0.f,0.f,0.f}};
    const int grow = block_row + lr;
    const bool arow_ok = (grow < M);
    const float* Aptr = A + (size_t)grow * K;

    for (int k0 = 0; k0 < K; k0 += 16) {
        float4 av = make_float4(0.f, 0.f, 0.f, 0.f);
        if (arow_ok) av = *(const float4*)(Aptr + k0 + lk);
        As2[lk+0][lr] = av.x; As2[lk+1][lr] = av.y; As2[lk+2][lr] = av.z; As2[lk+3][lr] = av.w;
        *(float4*)&Bs2[brow][bc] = *(const float4*)(W + (size_t)(k0 + brow) * DD + bc);
        __syncthreads();
        #pragma unroll
        for (int k = 0; k < 16; ++k) {
            float4 a = *(const float4*)&As2[k][ty << 2];
            float4 b = *(const float4*)&Bs2[k][tx << 2];
            acc[0][0] += a.x*b.x; acc[0][1] += a.x*b.y; acc[0][2] += a.x*b.z; acc[0][3] += a.x*b.w;
            acc[1][0] += a.y*b.x; acc[1][1] += a.y*b.y; acc[1][2] += a.y*b.z; acc[1][3] += a.y*b.w;
            acc[2][0] += a.z*b.x; acc[2][1] += a.z*b.y; acc[2][2] += a.z*b.z; acc[2][3] += a.z*b.w;
            acc[3][0] += a.w*b.x; acc[3][1] += a.w*b.y; acc[3][2] += a.w*b.z; acc[3][3] += a.w*b.w;
        }
        __syncthreads();
    }
    const float4 bv = *(const float4*)(bias + (tx << 2));
    #pragma unroll
    for (int i = 0; i < 4; ++i) {
        int row = block_row + (ty << 2) + i;
        if (row < M) {
            float4 o = make_float4(acc[i][0] + bv.x, acc[i][1] + bv.y,
                                   acc[i][2] + bv.z, acc[i][3] + bv.w);
            *(float4*)(C + (size_t)row * ldc + (tx << 2)) = o;
        }
    }
}

__global__ __launch_bounds__(256) void l2norm_rows(float* __restrict__ x, int nrows, int ld)
{
    int row  = blockIdx.x * 4 + (threadIdx.x >> 6);
    int lane = threadIdx.x & 63;
    if (row >= nrows) return;
    float v = x[(size_t)row * ld + lane];
    float s = v * v;
    #pragma unroll
    for (int off = 32; off > 0; off >>= 1) s += __shfl_xor(s, off);
    float n = sqrtf(s);
    x[(size_t)row * ld + lane] = v / fmaxf(n, 1e-12f);
}

__global__ __launch_bounds__(256) void scale4(const float4* __restrict__ src,
                                              float4* __restrict__ dst, int n4)
{
    int i = blockIdx.x * 256 + threadIdx.x;
    if (i < n4) {
        float4 v = src[i];
        dst[i] = make_float4(ALPHA_*v.x, ALPHA_*v.y, ALPHA_*v.z, ALPHA_*v.w);
    }
}

__global__ __launch_bounds__(256) void spmm_atomic(
    const float* __restrict__ vals, const int* __restrict__ rows,
    const int* __restrict__ cols, const float* __restrict__ x,
    float* __restrict__ out, int nnz)
{
    long long tid = (long long)blockIdx.x * 256 + threadIdx.x;
    int g = (int)(tid >> 4);
    if (g >= nnz) return;
    int lane = (int)(tid & 15);
    float v = vals[g];
    int r = rows[g], c = cols[g];
    float4 xv = *((const float4*)(x + (size_t)c * DD) + lane);
    float* o = out + (size_t)r * DD + (lane << 2);
    atomicAdd(o + 0, v * xv.x);
    atomicAdd(o + 1, v * xv.y);
    atomicAdd(o + 2, v * xv.z);
    atomicAdd(o + 3, v * xv.w);
}

__global__ __launch_bounds__(256) void finalize_k(
    const float4* __restrict__ egoI, const float4* __restrict__ egoT,
    float4* __restrict__ out)
{
    int tid = blockIdx.x * 256 + threadIdx.x;
    int row = tid >> 5, q = tid & 31;
    if (row >= NTOT) return;
    float4 v = (q < 16) ? egoI[(size_t)row * 16 + q] : egoT[(size_t)row * 16 + (q - 16)];
    out[tid] = v;
}

// ============================================================================
extern "C" void kernel_launch(void* const* d_in, const int* in_sizes, int n_in,
                              void* d_out, int out_size, void* d_ws, size_t ws_size,
                              hipStream_t stream)
{
    const float* image_feats = (const float*)d_in[0];
    const float* text_feats  = (const float*)d_in[1];
    const float* image_pref  = (const float*)d_in[2];
    const float* text_pref   = (const float*)d_in[3];
    const float* W_img       = (const float*)d_in[4];
    const float* b_img       = (const float*)d_in[5];
    const float* W_txt       = (const float*)d_in[6];
    const float* b_txt       = (const float*)d_in[7];
    const float* adj_vals    = (const float*)d_in[8];
    const int*   adj_rows    = (const int*)d_in[9];
    const int*   adj_cols    = (const int*)d_in[10];

    float* out = (float*)d_out;
    char*  ws  = (char*)d_ws;

    const size_t OFF_PTMP   = 0;             // 51,200,000 B
    const size_t OFF_SPAIR  = 51200000;      // 51,200,000 B
    const size_t OFF_RSTART = 102400000;     // 600,016 B
    const size_t OFF_SMALL  = 103000016;     // gbhist/gbstart/gbcur
    const size_t OFF_WFI    = 103004160;     // 524,288 B  (img W frags)
    const size_t OFF_WFT    = 103528448;     // 49,152 B   (txt W frags)
    const size_t OFF_XB0    = 103577600;     // 38,400,000 B
    const size_t OFF_XB1    = 141977600;     // 38,400,000 B
    const size_t NEED       = 180377600;

    if (ws_size >= NEED) {
        int2* ptmp    = (int2*)(ws + OFF_PTMP);
        int2* spair   = (int2*)(ws + OFF_SPAIR);
        int*  rstart  = (int*) (ws + OFF_RSTART);
        int*  gbhist  = (int*) (ws + OFF_SMALL);
        int*  gbstart = gbhist + 320;
        int*  gbcur   = gbhist + 640;
        u32*  WfI     = (u32*) (ws + OFF_WFI);
        u32*  WfT     = (u32*) (ws + OFF_WFT);
        u32*  Xb0     = (u32*) (ws + OFF_XB0);
        u32*  Xb1     = (u32*) (ws + OFF_XB1);
        u16*  items_bf = (u16*)Xb0 + (size_t)N_USERS * 128;

        // ---- ego0 users (bf16 shadow only) + W fragment conversion ----
        build_user<<<(N_USERS * 16) / 256, 256, 0, stream>>>(
            (const float4*)image_pref, (const float4*)text_pref, (ushort4*)Xb0);
        convert_wf<<<(4096 / 32 * 1024) / 256, 256, 0, stream>>>(W_img, WfI, 4096);
        convert_wf<<<(384 / 32 * 1024) / 256, 256, 0, stream>>>(W_txt, WfT, 384);

        // ---- bucketed 2-pass row sort (packed; also produces rstart) ----
        hipMemsetAsync(gbhist, 0, 320 * sizeof(int), stream);
        bucket_cnt<<<NCH, 256, 0, stream>>>(adj_rows, gbhist);
        scan_nbuck<<<1, 512, 0, stream>>>(gbhist, gbstart, gbcur);
        sort_pass1<<<NCH, 256, 0, stream>>>(adj_vals, adj_rows, adj_cols, gbcur, ptmp);
        sort_pass2<<<NBUCK, 256, 0, stream>>>(ptmp, gbstart, spair, rstart);
        set_tail<<<1, 64, 0, stream>>>(rstart);

        // ---- item GEMMs: MFMA, fused bias + L2-norm, bf16 out ----
        gemm_mfma<<<(N_ITEMS + 63) / 64, 256, 0, stream>>>(
            image_feats, (const int4*)WfI, b_img, items_bf, N_ITEMS, 4096);
        gemm_mfma<<<(N_ITEMS + 63) / 64, 256, 0, stream>>>(
            text_feats, (const int4*)WfT, b_txt, items_bf + 64, N_ITEMS, 384);

        // ---- 2 propagation layers ----
        spmm_wave<<<NTOT / 4, 256, 0, stream>>>(spair, rstart, Xb0,
                                                (float*)nullptr, Xb1);
        spmm_wave<<<NTOT / 4, 256, 0, stream>>>(spair, rstart, Xb1,
                                                out, (u32*)nullptr);
        return;
    }

    // ================= fallback: round-1 atomic path =================
    float* wsf = (float*)d_ws;
    float* Ai = wsf;
    float* At = wsf + SZ;
    float* Bi = out;
    float* Bt = out + SZ;

    const int n4_pref = N_USERS * DD / 4;
    const int n4_ego  = (int)(SZ / 4);

    copy4<<<n4_pref / 256, 256, 0, stream>>>((const float4*)image_pref, (float4*)Ai, n4_pref);
    copy4<<<n4_pref / 256, 256, 0, stream>>>((const float4*)text_pref,  (float4*)At, n4_pref);

    gemm_bias<<<(N_ITEMS + 63) / 64, 256, 0, stream>>>(image_feats, W_img, b_img,
                                                       Ai + (size_t)N_USERS * DD, N_ITEMS, 4096, DD);
    gemm_bias<<<(N_ITEMS + 63) / 64, 256, 0, stream>>>(text_feats,  W_txt, b_txt,
                                                       At + (size_t)N_USERS * DD, N_ITEMS, 384, DD);
    l2norm_rows<<<(N_ITEMS + 3) / 4, 256, 0, stream>>>(Ai + (size_t)N_USERS * DD, N_ITEMS, DD);
    l2norm_rows<<<(N_ITEMS + 3) / 4, 256, 0, stream>>>(At + (size_t)N_USERS * DD, N_ITEMS, DD);

    const int spmm_blocks = (int)(((long long)NNZV * 16 + 255) / 256);

    scale4<<<(n4_ego + 255) / 256, 256, 0, stream>>>((const float4*)Ai, (float4*)Bi, n4_ego);
    spmm_atomic<<<spmm_blocks, 256, 0, stream>>>(adj_vals, adj_rows, adj_cols, Ai, Bi, NNZV);
    scale4<<<(n4_ego + 255) / 256, 256, 0, stream>>>((const float4*)At, (float4*)Bt, n4_ego);
    spmm_atomic<<<spmm_blocks, 256, 0, stream>>>(adj_vals, adj_rows, adj_cols, At, Bt, NNZV);

    scale4<<<(n4_ego + 255) / 256, 256, 0, stream>>>((const float4*)Bi, (float4*)Ai, n4_ego);
    spmm_atomic<<<spmm_blocks, 256, 0, stream>>>(adj_vals, adj_rows, adj_cols, Bi, Ai, NNZV);
    scale4<<<(n4_ego + 255) / 256, 256, 0, stream>>>((const float4*)Bt, (float4*)At, n4_ego);
    spmm_atomic<<<spmm_blocks, 256, 0, stream>>>(adj_vals, adj_rows, adj_cols, Bt, At, NNZV);

    finalize_k<<<(NTOT * 32) / 256, 256, 0, stream>>>((const float4*)Ai, (const float4*)At,
                                                      (float4*)out);
}